// Round 10
// baseline (677.300 us; speedup 1.0000x reference)
//
#include <hip/hip_runtime.h>
#include <math.h>

typedef unsigned short u16;
typedef unsigned int   u32;
typedef unsigned long long u64;
typedef float  v16f __attribute__((ext_vector_type(16)));
typedef short  v8s  __attribute__((ext_vector_type(8)));
typedef unsigned int v4u __attribute__((ext_vector_type(4)));

__device__ __forceinline__ float sigf(float x) { return 1.0f / (1.0f + __expf(-x)); }
__device__ __forceinline__ float tanhfast(float x) { return 2.0f / (1.0f + __expf(-2.0f * x)) - 1.0f; }
__device__ __forceinline__ u16 f2bf(float f) {
    u32 x = __float_as_uint(f);
    u32 r = (x + 0x7fffu + ((x >> 16) & 1u)) >> 16;   // RNE
    return (u16)r;
}

// Agent-scope (sc1) 16B record ops (R13-proven): coherence point = IC.
// Two loads issued before one vmcnt wait -> both record fetches overlap.
#define LD2SYS(v0, v1, p0, p1)                                                \
    asm volatile("global_load_dwordx4 %0, %2, off sc1\n\t"                    \
                 "global_load_dwordx4 %1, %3, off sc1\n\t"                    \
                 "s_waitcnt vmcnt(0)"                                         \
                 : "=&v"(v0), "=&v"(v1)                                       \
                 : "v"(p0), "v"(p1)                                           \
                 : "memory")

// Fire-and-forget record store (drained by next step's LD2SYS vmcnt(0);
// tag+data are one 16B store so a consumer never sees tag without data).
#define ST16SYS(p, v)                                                         \
    asm volatile("global_store_dwordx4 %0, %1, off sc1"                       \
                 :: "v"(p), "v"(v) : "memory")

// ---------------------------------------------------------------------
// Conv-as-MFMA constants (verified R4)
// ---------------------------------------------------------------------
#define KE        19
#define SLAB      2048
#define G0_OFF    0
#define G1_OFF    (3 * KE * SLAB)
#define G2_OFF    (7 * KE * SLAB)
#define WKR_TOT   (12 * KE * SLAB)
#define XSTR      312

__global__ __launch_bounds__(256) void k_cprep(const float* __restrict__ w3,
                                               const float* __restrict__ w4,
                                               const float* __restrict__ w5,
                                               u16* __restrict__ wkr) {
    const int gid = blockIdx.x * 256 + threadIdx.x;
    int g, rem;
    if (gid < G1_OFF)      { g = 0; rem = gid; }
    else if (gid < G2_OFF) { g = 1; rem = gid - G1_OFF; }
    else                   { g = 2; rem = gid - G2_OFF; }
    const int fs = 3 + g;
    const int j  = rem & 7;
    const int q  = (rem >> 3) & 1;
    const int f  = (rem >> 4) & 127;
    const int t  = rem >> 11;
    const int ke = t % KE;
    const int kk = t / KE;
    const int e  = ke * 16 + q * 8 + j;
    float v = 0.0f;
    if (f < 100 && e < 300) {
        const float* w = (g == 0) ? w3 : (g == 1) ? w4 : w5;
        v = w[((size_t)f * 300 + e) * fs + kk];
    }
    wkr[gid] = f2bf(v);
}

// =====================================================================
// K1: conv via MFMA (unchanged, R11-proven)
// =====================================================================
__global__ __launch_bounds__(384) void k_conv_mfma(const int* __restrict__ dlg,
                                                   const float* __restrict__ emb,
                                                   const u16* __restrict__ wkr,
                                                   const float* __restrict__ b3,
                                                   const float* __restrict__ b4,
                                                   const float* __restrict__ b5,
                                                   float* __restrict__ feat) {
    __shared__ u16 xT[104 * XSTR];
    __shared__ int toks[96];
    const int u2  = blockIdx.x;
    const int tid = threadIdx.x;
    if (tid < 96) toks[tid] = dlg[u2 * 96 + tid];
    __syncthreads();
    for (int i = tid; i < 96 * 75; i += 384) {
        int t  = i / 75;
        int e4 = i - t * 75;
        int utt = (t >= 48);
        int row = utt * 52 + (t - utt * 48);
        float4 v = *(const float4*)(emb + (size_t)toks[t] * 300 + e4 * 4);
        uint2 o;
        o.x = (u32)f2bf(v.x) | ((u32)f2bf(v.y) << 16);
        o.y = (u32)f2bf(v.z) | ((u32)f2bf(v.w) << 16);
        *(uint2*)&xT[row * XSTR + e4 * 4] = o;
    }
    for (int i = tid; i < 8 * (XSTR / 2); i += 384) {
        int r = i / (XSTR / 2);
        int c = i - r * (XSTR / 2);
        int row = (r < 4) ? (48 + r) : (96 + r - 4);
        *(u32*)&xT[row * XSTR + c * 2] = 0;
    }
    __syncthreads();

    const int wv   = tid >> 6;
    const int lane = tid & 63;
    const int m    = lane & 31;
    const int q    = lane >> 5;

    int abase[3];
#pragma unroll
    for (int mt = 0; mt < 3; ++mt) {
        int r = mt * 32 + m;
        int utt = (r >= 48);
        int p = r - utt * 48;
        abase[mt] = (utt * 52 + p) * XSTR + q * 8;
    }

    int gA, ntA, gB, ntB, kkA, kkB;
    if (wv < 4) { gA = 0; ntA = wv; gB = 2; ntB = wv; kkA = 3; kkB = 5; }
    else        { gA = 1; ntA = (wv - 4) * 2; gB = 1; ntB = ntA + 1; kkA = 4; kkB = 4; }
    const int goffA = (gA == 0) ? G0_OFF : (gA == 1) ? G1_OFF : G2_OFF;
    const int goffB = (gB == 0) ? G0_OFF : (gB == 1) ? G1_OFF : G2_OFF;
    const u16* wA = wkr + goffA + ((ntA * 32 + m) * 2 + q) * 8;
    const u16* wB = wkr + goffB + ((ntB * 32 + m) * 2 + q) * 8;

    v16f accA[3], accB[3];
#pragma unroll
    for (int mt = 0; mt < 3; ++mt) {
#pragma unroll
        for (int r = 0; r < 16; ++r) { accA[mt][r] = 0.0f; accB[mt][r] = 0.0f; }
    }

    const int kmin = (kkA < kkB) ? kkA : kkB;   // waves0-3: 3, waves4-5: 4
    const u16* pA = wA;
    const u16* pB = wB;
    v8s bfA = *(const v8s*)pA;
    v8s bfB = *(const v8s*)pB;
    for (int kk = 0; kk < kmin; ++kk) {
        const int xshift = kk * XSTR;
        for (int ke = 0; ke < KE; ++ke) {
            v8s cA = bfA, cB = bfB;
            pA += SLAB; pB += SLAB;
            bfA = *(const v8s*)pA;             // prefetch (harmless overread at end)
            bfB = *(const v8s*)pB;
            const int xcol = xshift + ke * 16;
#pragma unroll
            for (int mt = 0; mt < 3; ++mt) {
                v8s af = *(const v8s*)&xT[abase[mt] + xcol];
                accA[mt] = __builtin_amdgcn_mfma_f32_32x32x16_bf16(af, cA, accA[mt], 0, 0, 0);
                accB[mt] = __builtin_amdgcn_mfma_f32_32x32x16_bf16(af, cB, accB[mt], 0, 0, 0);
            }
        }
    }
    for (int kk = kmin; kk < kkB; ++kk) {
        const int xshift = kk * XSTR;
        for (int ke = 0; ke < KE; ++ke) {
            v8s cB = bfB;
            pB += SLAB;
            bfB = *(const v8s*)pB;
            const int xcol = xshift + ke * 16;
#pragma unroll
            for (int mt = 0; mt < 3; ++mt) {
                v8s af = *(const v8s*)&xT[abase[mt] + xcol];
                accB[mt] = __builtin_amdgcn_mfma_f32_32x32x16_bf16(af, cB, accB[mt], 0, 0, 0);
            }
        }
    }

    const int PP[3] = {46, 45, 44};
#pragma unroll
    for (int which = 0; which < 2; ++which) {
        const int g  = which ? gB : gA;
        const int nt = which ? ntB : ntA;
        const v16f* acc = which ? accB : accA;
        const float* bg = (g == 0) ? b3 : (g == 1) ? b4 : b5;
        const int f = nt * 32 + m;
        const float bias = (f < 100) ? bg[f] : 0.0f;
        const int Pg = PP[g];
        float v0 = -1e30f, v1 = -1e30f;
#pragma unroll
        for (int mt = 0; mt < 3; ++mt) {
#pragma unroll
            for (int reg = 0; reg < 16; ++reg) {
                int row = (reg & 3) + 8 * (reg >> 2) + 4 * q;
                int r = mt * 32 + row;
                int utt = (r >= 48);
                int p = r - utt * 48;
                if (p < Pg) {
                    float val = acc[mt][reg] + bias;
                    if (utt) v1 = fmaxf(v1, val); else v0 = fmaxf(v0, val);
                }
            }
        }
        v0 = fmaxf(v0, __shfl_xor(v0, 32, 64));
        v1 = fmaxf(v1, __shfl_xor(v1, 32, 64));
        if (q == 0 && f < 100) {
            feat[((size_t)(u2 * 2 + 0)) * 300 + g * 100 + f] = fmaxf(0.0f, v0);
            feat[((size_t)(u2 * 2 + 1)) * 300 + g * 100 + f] = fmaxf(0.0f, v1);
        }
    }
}

// =====================================================================
// K2: xg GEMM; output in MFMA C-fragment order (unchanged)
// =====================================================================
__global__ __launch_bounds__(256) void k_xg(const float* __restrict__ feat,
                                            const float* __restrict__ wih_f, const float* __restrict__ bih_f,
                                            const float* __restrict__ bhh_f,
                                            const float* __restrict__ wih_r, const float* __restrict__ bih_r,
                                            const float* __restrict__ bhh_r,
                                            float* __restrict__ xgF) {
    __shared__ float fls[300 * 36];
    const int bx  = blockIdx.x;
    const int dir = bx >> 8;
    const int t   = (bx >> 2) & 63;
    const int gc  = bx & 3;
    const int tid = threadIdx.x;
    for (int i = tid; i < 32 * 300; i += 256) {
        int b = i / 300;
        int d = i - b * 300;
        fls[d * 36 + b] = feat[((size_t)b * 64 + t) * 300 + d];
    }
    __syncthreads();
    const int g = gc * 256 + tid;
    const float* wih = dir ? wih_r : wih_f;
    const float* bih = dir ? bih_r : bih_f;
    const float* bhh = dir ? bhh_r : bhh_f;
    const float* wr  = wih + (size_t)g * 300;
    const float bias = bih[g] + bhh[g];
    float acc[32];
#pragma unroll
    for (int b = 0; b < 32; ++b) acc[b] = 0.0f;
    for (int d = 0; d < 300; d += 4) {
        float4 wv = *(const float4*)(wr + d);
#pragma unroll
        for (int j = 0; j < 4; ++j) {
            float w = (j == 0) ? wv.x : (j == 1) ? wv.y : (j == 2) ? wv.z : wv.w;
            const float* r = &fls[(d + j) * 36];
#pragma unroll
            for (int bq = 0; bq < 8; ++bq) {
                float4 x = *(const float4*)(r + bq * 4);
                acc[bq * 4 + 0] = fmaf(w, x.x, acc[bq * 4 + 0]);
                acc[bq * 4 + 1] = fmaf(w, x.y, acc[bq * 4 + 1]);
                acc[bq * 4 + 2] = fmaf(w, x.z, acc[bq * 4 + 2]);
                acc[bq * 4 + 3] = fmaf(w, x.w, acc[bq * 4 + 3]);
            }
        }
    }
    const int jj      = tid;
    const int js      = jj >> 6;
    const int n_local = ((jj & 63) << 2) | gc;
    const int nt      = n_local >> 5;
    const int lane_lo = n_local & 31;
    float* base = xgF + (((size_t)(dir * 64 + t) * 32) + js * 8 + nt) * 1024;
#pragma unroll
    for (int b = 0; b < 32; ++b) {
        int q    = (b >> 2) & 1;
        int reg  = (b & 3) + ((b >> 3) << 2);
        base[reg * 64 + lane_lo + (q << 5)] = acc[b] + bias;
    }
}

// =====================================================================
// K_prep3: w_hh -> MFMA B-fragment shards (unchanged)
// =====================================================================
__global__ __launch_bounds__(256) void k_prep3(const float* __restrict__ whh_f,
                                               const float* __restrict__ whh_r,
                                               u16* __restrict__ wpk3) {
    const int gid  = blockIdx.x * 256 + threadIdx.x;    // [0, 524288)
    const int j    = gid & 7;
    const int lane = (gid >> 3) & 63;
    const int kt   = (gid >> 9) & 15;
    const int nt   = (gid >> 13) & 7;
    const int js   = (gid >> 16) & 3;
    const int dir  = (gid >> 18) & 1;
    const int n_local = nt * 32 + (lane & 31);
    const int jjl  = n_local >> 2;
    const int gate = n_local & 3;
    const int k    = kt * 16 + (lane >> 5) * 8 + j;
    const int row  = gate * 256 + js * 64 + jjl;
    const float* whh = dir ? whh_r : whh_f;
    wpk3[gid] = f2bf(whh[(size_t)row * 256 + k]);
}

// k_init: zero all 8192 h-exchange records (2 dir x 2 parity x 2048)
__global__ __launch_bounds__(256) void k_init(v4u* __restrict__ hxrec) {
    const int id = blockIdx.x * 256 + threadIdx.x;
    v4u z; z[0] = 0u; z[1] = 0u; z[2] = 0u; z[3] = 0u;
    hxrec[id] = z;
}

// =====================================================================
// K3 v16 = v15 + __launch_bounds__(512, 2).  R20 post-mortem: without a
// waves/EU floor, hipcc targets 4 waves/SIMD and caps the allocator at
// 128 VGPRs (observed 116 in R15 AND R20) -> Bf0/Bf1 rematerialized from
// L2 every step (the 353us = W-streaming). Declaring 2 waves/EU lifts
// the cap to 256 VGPRs so both B-fragment sets (128 VGPR) stay resident.
// Only 4 blocks run on 256 CUs, so occupancy cost is irrelevant.
// Everything else byte-identical to the R20 kernel (absmax 0.0078).
// =====================================================================
__global__ __launch_bounds__(512, 2) void k_lstm3(const u16* __restrict__ wpk3,
                                                  const float* __restrict__ xgF,
                                                  u32* __restrict__ hxrec,
                                                  float* __restrict__ hseq) {
    __shared__ u32   hbuf[32 * 132];          // full h (256/batch) as bf16 pairs
    __shared__ float sl0[8 * 32 * 36];        // per-wave transpose slab (nt0)
    __shared__ float sl1[8 * 32 * 36];        // per-wave transpose slab (nt1)
    const int dir = blockIdx.x >> 1;
    const int jh  = blockIdx.x & 1;           // gate half: js in {2jh, 2jh+1}
    const int tid = threadIdx.x;
    const int w   = tid >> 6;                 // wave 0..7
    const int l   = tid & 63;
    const int m   = l & 31;
    const int q   = l >> 5;

    const int sub = w >> 2;                   // 0: js=2jh, 1: js=2jh+1
    const int jsw = jh * 2 + sub;
    const int nt0 = w & 3;
    const int nt1 = (w & 3) + 4;

    // B-fragments for both n-tiles: 32 v8s = 128 VGPRs, resident.
    v8s Bf0[16], Bf1[16];
    {
        const u16* wb0 = wpk3 + ((((size_t)dir * 4 + jsw) * 8 + nt0) * 16) * 512 + (size_t)l * 8;
        const u16* wb1 = wpk3 + ((((size_t)dir * 4 + jsw) * 8 + nt1) * 16) * 512 + (size_t)l * 8;
#pragma unroll
        for (int kt = 0; kt < 16; ++kt) {
            Bf0[kt] = *(const v8s*)(wb0 + kt * 512);
            Bf1[kt] = *(const v8s*)(wb1 + kt * 512);
        }
    }

    // EW ownership (wave-local, R18 mapping): lane -> (batch bl, j-pair jp)
    const int jp = l & 1;
    const int bl = l >> 1;
    float cst[8], hval[8];
#pragma unroll
    for (int c = 0; c < 8; ++c) { cst[c] = 0.0f; hval[c] = 0.0f; }

    float* hout = hseq + (size_t)dir * 64 * 32 * 256;
    u32* hx_d   = hxrec + (size_t)dir * 2 * 2048 * 4;   // u32 units
    const u32* hx0 = hx_d;                    // parity-0 slot
    const u32* hx1 = hx_d + 2048 * 4;         // parity-1 slot

    // consumer: peer half's 32 q64-slots x 32 batches = 1024 recs, 2/thread
    int roff[2], hoff[2];
#pragma unroll
    for (int i = 0; i < 2; ++i) {
        int flat = i * 512 + tid;
        int b    = flat >> 5;
        int r    = flat & 31;
        int q64  = (1 - jh) * 32 + r;
        roff[i]  = (b * 64 + q64) * 4;
        hoff[i]  = b * 132 + q64 * 2;
    }
    // producer slots (own 2 record q64 indices)
    const int q64a  = jsw * 16 + 2 * nt0 + jp;
    const int q64b  = jsw * 16 + 2 * nt1 + jp;
    const int woff0 = (bl * 64 + q64a) * 4;
    const int woff1 = (bl * 64 + q64b) * 4;
    const int hown0 = bl * 132 + q64a * 2;
    const int hown1 = bl * 132 + q64b * 2;

    float* s0 = &sl0[w * 32 * 36];
    float* s1 = &sl1[w * 32 * 36];

    for (int s = 0; s < 64; ++s) {
        const int t = dir ? (63 - s) : s;
        // acc init from xg (serial load, R13-style; prefetch was neutral in R18)
        v16f acc0, acc1;
        {
            const float* xb0 = xgF + (((size_t)(dir * 64 + t) * 32) + jsw * 8 + nt0) * 1024 + l;
            const float* xb1 = xgF + (((size_t)(dir * 64 + t) * 32) + jsw * 8 + nt1) * 1024 + l;
#pragma unroll
            for (int r = 0; r < 16; ++r) { acc0[r] = xb0[r * 64]; acc1[r] = xb1[r * 64]; }
        }

        if (s > 0) {
            // own packs (hval of step s-1) into hbuf
            u64 pk0 = (u64)f2bf(hval[0]) | ((u64)f2bf(hval[1]) << 16)
                    | ((u64)f2bf(hval[2]) << 32) | ((u64)f2bf(hval[3]) << 48);
            u64 pk1 = (u64)f2bf(hval[4]) | ((u64)f2bf(hval[5]) << 16)
                    | ((u64)f2bf(hval[6]) << 32) | ((u64)f2bf(hval[7]) << 48);
            *(u64*)&hbuf[hown0] = pk0;
            *(u64*)&hbuf[hown1] = pk1;
            // spin for the single peer's records (tag == s)
            const u32* hxs = (s & 1) ? hx1 : hx0;
            const u32* p0 = hxs + roff[0];
            const u32* p1 = hxs + roff[1];
            v4u v0, v1;
            LD2SYS(v0, v1, p0, p1);
            const u32 ts = (u32)s;
            u32 guard = 0;
            while (v0[2] != ts || v1[2] != ts) {
                if (++guard > (1u << 22)) break;
                LD2SYS(v0, v1, p0, p1);
            }
            *(u64*)&hbuf[hoff[0]] = (u64)v0[0] | ((u64)v0[1] << 32);
            *(u64*)&hbuf[hoff[1]] = (u64)v1[0] | ((u64)v1[1] << 32);
        } else {
            for (int i = tid; i < 32 * 132; i += 512) hbuf[i] = 0u;
        }
        __syncthreads();                      // A: hbuf(s) ready

        // MFMA: af in 4-kt chunks (16 VGPR transient); kt ascending per acc
#pragma unroll
        for (int cc = 0; cc < 4; ++cc) {
            v8s a0 = *(const v8s*)&hbuf[m * 132 + (4 * cc + 0) * 8 + q * 4];
            v8s a1 = *(const v8s*)&hbuf[m * 132 + (4 * cc + 1) * 8 + q * 4];
            v8s a2 = *(const v8s*)&hbuf[m * 132 + (4 * cc + 2) * 8 + q * 4];
            v8s a3 = *(const v8s*)&hbuf[m * 132 + (4 * cc + 3) * 8 + q * 4];
            acc0 = __builtin_amdgcn_mfma_f32_32x32x16_bf16(a0, Bf0[4 * cc + 0], acc0, 0, 0, 0);
            acc0 = __builtin_amdgcn_mfma_f32_32x32x16_bf16(a1, Bf0[4 * cc + 1], acc0, 0, 0, 0);
            acc0 = __builtin_amdgcn_mfma_f32_32x32x16_bf16(a2, Bf0[4 * cc + 2], acc0, 0, 0, 0);
            acc0 = __builtin_amdgcn_mfma_f32_32x32x16_bf16(a3, Bf0[4 * cc + 3], acc0, 0, 0, 0);
            acc1 = __builtin_amdgcn_mfma_f32_32x32x16_bf16(a0, Bf1[4 * cc + 0], acc1, 0, 0, 0);
            acc1 = __builtin_amdgcn_mfma_f32_32x32x16_bf16(a1, Bf1[4 * cc + 1], acc1, 0, 0, 0);
            acc1 = __builtin_amdgcn_mfma_f32_32x32x16_bf16(a2, Bf1[4 * cc + 2], acc1, 0, 0, 0);
            acc1 = __builtin_amdgcn_mfma_f32_32x32x16_bf16(a3, Bf1[4 * cc + 3], acc1, 0, 0, 0);
        }
        __syncthreads();                      // B: hbuf free for s+1

        // per-wave transposes (separate slabs -> no WAR hazard)
#pragma unroll
        for (int r = 0; r < 16; ++r) {
            int row = (r & 3) + 8 * (r >> 2) + 4 * q;
            s0[row * 36 + m] = acc0[r];
            s1[row * 36 + m] = acc1[r];
        }
        // wave-local W->R ordering: compiler inserts lgkmcnt (same buffers)
#pragma unroll
        for (int c = 0; c < 4; ++c) {
            float4 gv = *(const float4*)&s0[bl * 36 + jp * 16 + c * 4];
            float i_ = sigf(gv.x), f_ = sigf(gv.y);
            float g_ = tanhfast(gv.z), o_ = sigf(gv.w);
            cst[c]  = f_ * cst[c] + i_ * g_;
            hval[c] = o_ * tanhfast(cst[c]);
        }
#pragma unroll
        for (int c = 0; c < 4; ++c) {
            float4 gv = *(const float4*)&s1[bl * 36 + jp * 16 + c * 4];
            float i_ = sigf(gv.x), f_ = sigf(gv.y);
            float g_ = tanhfast(gv.z), o_ = sigf(gv.w);
            cst[4 + c]  = f_ * cst[4 + c] + i_ * g_;
            hval[4 + c] = o_ * tanhfast(cst[4 + c]);
        }

        {
            u64 pk0 = (u64)f2bf(hval[0]) | ((u64)f2bf(hval[1]) << 16)
                    | ((u64)f2bf(hval[2]) << 32) | ((u64)f2bf(hval[3]) << 48);
            u64 pk1 = (u64)f2bf(hval[4]) | ((u64)f2bf(hval[5]) << 16)
                    | ((u64)f2bf(hval[6]) << 32) | ((u64)f2bf(hval[7]) << 48);
            v4u rec0, rec1;
            rec0[0] = (u32)pk0; rec0[1] = (u32)(pk0 >> 32); rec0[2] = (u32)(s + 1); rec0[3] = 0u;
            rec1[0] = (u32)pk1; rec1[1] = (u32)(pk1 >> 32); rec1[2] = (u32)(s + 1); rec1[3] = 0u;
            u32* pw0 = (u32*)(((s & 1) ? hx0 : hx1) + woff0);   // parity (s+1)&1
            u32* pw1 = (u32*)(((s & 1) ? hx0 : hx1) + woff1);
            ST16SYS(pw0, rec0);
            ST16SYS(pw1, rec1);
            float* ho = &hout[((size_t)t * 32 + bl) * 256];
            *(float4*)&ho[jsw * 64 + 8 * nt0 + 4 * jp] = make_float4(hval[0], hval[1], hval[2], hval[3]);
            *(float4*)&ho[jsw * 64 + 8 * nt1 + 4 * jp] = make_float4(hval[4], hval[5], hval[6], hval[7]);
        }
    }
}

// =====================================================================
// K4: head (unchanged)
// =====================================================================
__global__ __launch_bounds__(256) void k_head(const float* __restrict__ hseq,
                                              const float* __restrict__ hw,
                                              const float* __restrict__ hb,
                                              float* __restrict__ out) {
    const int id = blockIdx.x * 256 + threadIdx.x;
    const int o  = id & 31;
    const int u  = id >> 5;
    const int b  = u >> 6, t = u & 63;
    const float* pf = hseq + ((size_t)t * 32 + b) * 256;
    const float* pr = hseq + (size_t)64 * 32 * 256 + ((size_t)t * 32 + b) * 256;
    const float* wo = hw + (size_t)o * 512;
    float acc = hb[o];
    for (int j = 0; j < 256; j += 4) {
        float4 wa = *(const float4*)(wo + j);
        float4 wb = *(const float4*)(wo + 256 + j);
        float4 fa = *(const float4*)(pf + j);
        float4 fb = *(const float4*)(pr + j);
        acc = fmaf(wa.x, fa.x, acc); acc = fmaf(wa.y, fa.y, acc);
        acc = fmaf(wa.z, fa.z, acc); acc = fmaf(wa.w, fa.w, acc);
        acc = fmaf(wb.x, fb.x, acc); acc = fmaf(wb.y, fb.y, acc);
        acc = fmaf(wb.z, fb.z, acc); acc = fmaf(wb.w, fb.w, acc);
    }
    out[id] = sigf(acc);
}

// =====================================================================
extern "C" void kernel_launch(void* const* d_in, const int* in_sizes, int n_in,
                              void* d_out, int out_size, void* d_ws, size_t ws_size,
                              hipStream_t stream) {
    const int*   dlg   = (const int*)d_in[0];
    const float* emb   = (const float*)d_in[1];
    const float* w3    = (const float*)d_in[2];  const float* b3    = (const float*)d_in[3];
    const float* w4    = (const float*)d_in[4];  const float* b4    = (const float*)d_in[5];
    const float* w5    = (const float*)d_in[6];  const float* b5    = (const float*)d_in[7];
    const float* wih_f = (const float*)d_in[8];  const float* whh_f = (const float*)d_in[9];
    const float* bih_f = (const float*)d_in[10]; const float* bhh_f = (const float*)d_in[11];
    const float* wih_r = (const float*)d_in[12]; const float* whh_r = (const float*)d_in[13];
    const float* bih_r = (const float*)d_in[14]; const float* bhh_r = (const float*)d_in[15];
    const float* hw    = (const float*)d_in[16]; const float* hb    = (const float*)d_in[17];
    float* out = (float*)d_out;

    float* f     = (float*)d_ws;
    float* feat  = f;                         // 614400
    float* xgF   = f + 614400;                // 4194304
    float* hseq  = f + 4808704;               // 1048576
    u16*   wkr   = (u16*)(f + 5857280);       // 466944 u16
    u16*   wpk3  = (u16*)(f + 6090752);       // 524288 u16
    u32*   hxrec = (u32*)(f + 6352896);       // 8192 records x 16B
    // total ~25.5 MB

    hipLaunchKernelGGL(k_init, dim3(32), dim3(256), 0, stream, (v4u*)hxrec);
    hipLaunchKernelGGL(k_cprep, dim3(WKR_TOT / 256), dim3(256), 0, stream,
                       w3, w4, w5, wkr);
    hipLaunchKernelGGL(k_prep3, dim3(2048), dim3(256), 0, stream,
                       whh_f, whh_r, wpk3);
    hipLaunchKernelGGL(k_conv_mfma, dim3(1024), dim3(384), 0, stream,
                       dlg, emb, wkr, b3, b4, b5, feat);
    hipLaunchKernelGGL(k_xg, dim3(512), dim3(256), 0, stream,
                       feat, wih_f, bih_f, bhh_f, wih_r, bih_r, bhh_r, xgF);
    hipLaunchKernelGGL(k_lstm3, dim3(4), dim3(512), 0, stream,
                       wpk3, xgF, hxrec, hseq);
    hipLaunchKernelGGL(k_head, dim3(256), dim3(256), 0, stream,
                       hseq, hw, hb, out);
}

// Round 11
// 573.711 us; speedup vs baseline: 1.1806x; 1.1806x over previous
//
#include <hip/hip_runtime.h>
#include <math.h>

typedef unsigned short u16;
typedef unsigned int   u32;
typedef unsigned long long u64;
typedef float  v16f __attribute__((ext_vector_type(16)));
typedef short  v8s  __attribute__((ext_vector_type(8)));
typedef unsigned int v4u __attribute__((ext_vector_type(4)));

__device__ __forceinline__ float sigf(float x) { return 1.0f / (1.0f + __expf(-x)); }
__device__ __forceinline__ float tanhfast(float x) { return 2.0f / (1.0f + __expf(-2.0f * x)) - 1.0f; }
__device__ __forceinline__ u16 f2bf(float f) {
    u32 x = __float_as_uint(f);
    u32 r = (x + 0x7fffu + ((x >> 16) & 1u)) >> 16;   // RNE
    return (u16)r;
}

// ---- R22 pipelined poll primitives (agent scope; coherence point = IC) ----
// LD3NW: issue 3 record loads, NO wait (keeps the poll pipe full).
#define LD3NW(v0, v1, v2, p0, p1, p2)                                         \
    asm volatile("global_load_dwordx4 %0, %3, off sc1\n\t"                    \
                 "global_load_dwordx4 %1, %4, off sc1\n\t"                    \
                 "global_load_dwordx4 %2, %5, off sc1"                        \
                 : "=&v"(v0), "=&v"(v1), "=&v"(v2)                            \
                 : "v"(p0), "v"(p1), "v"(p2)                                  \
                 : "memory")

// WAIT3: wait until <=3 vector-mem ops outstanding (i.e. the OLDER poll
// set has landed). The "+v" in/outs make this asm the definition point of
// the polled registers, so their reads cannot be hoisted above the wait.
#define WAIT3(v0, v1, v2)                                                     \
    asm volatile("s_waitcnt vmcnt(3)"                                         \
                 : "+v"(v0), "+v"(v1), "+v"(v2) :: "memory")

// DRAIN: retire all outstanding vector-mem ops (late-landing poll loads
// must not clobber registers the allocator reuses after the spin).
#define DRAIN() asm volatile("s_waitcnt vmcnt(0)" ::: "memory")

// Fire-and-forget record store (tag+data in one 16B store: a consumer can
// never see the tag without its data; write-write order to the same slot is
// guaranteed by the DRAIN in the next step's spin).
#define ST16SYS(p, v)                                                         \
    asm volatile("global_store_dwordx4 %0, %1, off sc1"                       \
                 :: "v"(p), "v"(v) : "memory")

// ---------------------------------------------------------------------
// Conv-as-MFMA constants (verified R4)
// ---------------------------------------------------------------------
#define KE        19
#define SLAB      2048
#define G0_OFF    0
#define G1_OFF    (3 * KE * SLAB)
#define G2_OFF    (7 * KE * SLAB)
#define WKR_TOT   (12 * KE * SLAB)
#define XSTR      312

__global__ __launch_bounds__(256) void k_cprep(const float* __restrict__ w3,
                                               const float* __restrict__ w4,
                                               const float* __restrict__ w5,
                                               u16* __restrict__ wkr) {
    const int gid = blockIdx.x * 256 + threadIdx.x;
    int g, rem;
    if (gid < G1_OFF)      { g = 0; rem = gid; }
    else if (gid < G2_OFF) { g = 1; rem = gid - G1_OFF; }
    else                   { g = 2; rem = gid - G2_OFF; }
    const int fs = 3 + g;
    const int j  = rem & 7;
    const int q  = (rem >> 3) & 1;
    const int f  = (rem >> 4) & 127;
    const int t  = rem >> 11;
    const int ke = t % KE;
    const int kk = t / KE;
    const int e  = ke * 16 + q * 8 + j;
    float v = 0.0f;
    if (f < 100 && e < 300) {
        const float* w = (g == 0) ? w3 : (g == 1) ? w4 : w5;
        v = w[((size_t)f * 300 + e) * fs + kk];
    }
    wkr[gid] = f2bf(v);
}

// =====================================================================
// K1: conv via MFMA (unchanged, R11-proven)
// =====================================================================
__global__ __launch_bounds__(384) void k_conv_mfma(const int* __restrict__ dlg,
                                                   const float* __restrict__ emb,
                                                   const u16* __restrict__ wkr,
                                                   const float* __restrict__ b3,
                                                   const float* __restrict__ b4,
                                                   const float* __restrict__ b5,
                                                   float* __restrict__ feat) {
    __shared__ u16 xT[104 * XSTR];
    __shared__ int toks[96];
    const int u2  = blockIdx.x;
    const int tid = threadIdx.x;
    if (tid < 96) toks[tid] = dlg[u2 * 96 + tid];
    __syncthreads();
    for (int i = tid; i < 96 * 75; i += 384) {
        int t  = i / 75;
        int e4 = i - t * 75;
        int utt = (t >= 48);
        int row = utt * 52 + (t - utt * 48);
        float4 v = *(const float4*)(emb + (size_t)toks[t] * 300 + e4 * 4);
        uint2 o;
        o.x = (u32)f2bf(v.x) | ((u32)f2bf(v.y) << 16);
        o.y = (u32)f2bf(v.z) | ((u32)f2bf(v.w) << 16);
        *(uint2*)&xT[row * XSTR + e4 * 4] = o;
    }
    for (int i = tid; i < 8 * (XSTR / 2); i += 384) {
        int r = i / (XSTR / 2);
        int c = i - r * (XSTR / 2);
        int row = (r < 4) ? (48 + r) : (96 + r - 4);
        *(u32*)&xT[row * XSTR + c * 2] = 0;
    }
    __syncthreads();

    const int wv   = tid >> 6;
    const int lane = tid & 63;
    const int m    = lane & 31;
    const int q    = lane >> 5;

    int abase[3];
#pragma unroll
    for (int mt = 0; mt < 3; ++mt) {
        int r = mt * 32 + m;
        int utt = (r >= 48);
        int p = r - utt * 48;
        abase[mt] = (utt * 52 + p) * XSTR + q * 8;
    }

    int gA, ntA, gB, ntB, kkA, kkB;
    if (wv < 4) { gA = 0; ntA = wv; gB = 2; ntB = wv; kkA = 3; kkB = 5; }
    else        { gA = 1; ntA = (wv - 4) * 2; gB = 1; ntB = ntA + 1; kkA = 4; kkB = 4; }
    const int goffA = (gA == 0) ? G0_OFF : (gA == 1) ? G1_OFF : G2_OFF;
    const int goffB = (gB == 0) ? G0_OFF : (gB == 1) ? G1_OFF : G2_OFF;
    const u16* wA = wkr + goffA + ((ntA * 32 + m) * 2 + q) * 8;
    const u16* wB = wkr + goffB + ((ntB * 32 + m) * 2 + q) * 8;

    v16f accA[3], accB[3];
#pragma unroll
    for (int mt = 0; mt < 3; ++mt) {
#pragma unroll
        for (int r = 0; r < 16; ++r) { accA[mt][r] = 0.0f; accB[mt][r] = 0.0f; }
    }

    const int kmin = (kkA < kkB) ? kkA : kkB;   // waves0-3: 3, waves4-5: 4
    const u16* pA = wA;
    const u16* pB = wB;
    v8s bfA = *(const v8s*)pA;
    v8s bfB = *(const v8s*)pB;
    for (int kk = 0; kk < kmin; ++kk) {
        const int xshift = kk * XSTR;
        for (int ke = 0; ke < KE; ++ke) {
            v8s cA = bfA, cB = bfB;
            pA += SLAB; pB += SLAB;
            bfA = *(const v8s*)pA;             // prefetch (harmless overread at end)
            bfB = *(const v8s*)pB;
            const int xcol = xshift + ke * 16;
#pragma unroll
            for (int mt = 0; mt < 3; ++mt) {
                v8s af = *(const v8s*)&xT[abase[mt] + xcol];
                accA[mt] = __builtin_amdgcn_mfma_f32_32x32x16_bf16(af, cA, accA[mt], 0, 0, 0);
                accB[mt] = __builtin_amdgcn_mfma_f32_32x32x16_bf16(af, cB, accB[mt], 0, 0, 0);
            }
        }
    }
    for (int kk = kmin; kk < kkB; ++kk) {
        const int xshift = kk * XSTR;
        for (int ke = 0; ke < KE; ++ke) {
            v8s cB = bfB;
            pB += SLAB;
            bfB = *(const v8s*)pB;
            const int xcol = xshift + ke * 16;
#pragma unroll
            for (int mt = 0; mt < 3; ++mt) {
                v8s af = *(const v8s*)&xT[abase[mt] + xcol];
                accB[mt] = __builtin_amdgcn_mfma_f32_32x32x16_bf16(af, cB, accB[mt], 0, 0, 0);
            }
        }
    }

    const int PP[3] = {46, 45, 44};
#pragma unroll
    for (int which = 0; which < 2; ++which) {
        const int g  = which ? gB : gA;
        const int nt = which ? ntB : ntA;
        const v16f* acc = which ? accB : accA;
        const float* bg = (g == 0) ? b3 : (g == 1) ? b4 : b5;
        const int f = nt * 32 + m;
        const float bias = (f < 100) ? bg[f] : 0.0f;
        const int Pg = PP[g];
        float v0 = -1e30f, v1 = -1e30f;
#pragma unroll
        for (int mt = 0; mt < 3; ++mt) {
#pragma unroll
            for (int reg = 0; reg < 16; ++reg) {
                int row = (reg & 3) + 8 * (reg >> 2) + 4 * q;
                int r = mt * 32 + row;
                int utt = (r >= 48);
                int p = r - utt * 48;
                if (p < Pg) {
                    float val = acc[mt][reg] + bias;
                    if (utt) v1 = fmaxf(v1, val); else v0 = fmaxf(v0, val);
                }
            }
        }
        v0 = fmaxf(v0, __shfl_xor(v0, 32, 64));
        v1 = fmaxf(v1, __shfl_xor(v1, 32, 64));
        if (q == 0 && f < 100) {
            feat[((size_t)(u2 * 2 + 0)) * 300 + g * 100 + f] = fmaxf(0.0f, v0);
            feat[((size_t)(u2 * 2 + 1)) * 300 + g * 100 + f] = fmaxf(0.0f, v1);
        }
    }
}

// =====================================================================
// K2: xg GEMM; output in MFMA C-fragment order (unchanged)
// =====================================================================
__global__ __launch_bounds__(256) void k_xg(const float* __restrict__ feat,
                                            const float* __restrict__ wih_f, const float* __restrict__ bih_f,
                                            const float* __restrict__ bhh_f,
                                            const float* __restrict__ wih_r, const float* __restrict__ bih_r,
                                            const float* __restrict__ bhh_r,
                                            float* __restrict__ xgF) {
    __shared__ float fls[300 * 36];
    const int bx  = blockIdx.x;
    const int dir = bx >> 8;
    const int t   = (bx >> 2) & 63;
    const int gc  = bx & 3;
    const int tid = threadIdx.x;
    for (int i = tid; i < 32 * 300; i += 256) {
        int b = i / 300;
        int d = i - b * 300;
        fls[d * 36 + b] = feat[((size_t)b * 64 + t) * 300 + d];
    }
    __syncthreads();
    const int g = gc * 256 + tid;
    const float* wih = dir ? wih_r : wih_f;
    const float* bih = dir ? bih_r : bih_f;
    const float* bhh = dir ? bhh_r : bhh_f;
    const float* wr  = wih + (size_t)g * 300;
    const float bias = bih[g] + bhh[g];
    float acc[32];
#pragma unroll
    for (int b = 0; b < 32; ++b) acc[b] = 0.0f;
    for (int d = 0; d < 300; d += 4) {
        float4 wv = *(const float4*)(wr + d);
#pragma unroll
        for (int j = 0; j < 4; ++j) {
            float w = (j == 0) ? wv.x : (j == 1) ? wv.y : (j == 2) ? wv.z : wv.w;
            const float* r = &fls[(d + j) * 36];
#pragma unroll
            for (int bq = 0; bq < 8; ++bq) {
                float4 x = *(const float4*)(r + bq * 4);
                acc[bq * 4 + 0] = fmaf(w, x.x, acc[bq * 4 + 0]);
                acc[bq * 4 + 1] = fmaf(w, x.y, acc[bq * 4 + 1]);
                acc[bq * 4 + 2] = fmaf(w, x.z, acc[bq * 4 + 2]);
                acc[bq * 4 + 3] = fmaf(w, x.w, acc[bq * 4 + 3]);
            }
        }
    }
    const int jj      = tid;
    const int js      = jj >> 6;
    const int n_local = ((jj & 63) << 2) | gc;
    const int nt      = n_local >> 5;
    const int lane_lo = n_local & 31;
    float* base = xgF + (((size_t)(dir * 64 + t) * 32) + js * 8 + nt) * 1024;
#pragma unroll
    for (int b = 0; b < 32; ++b) {
        int q    = (b >> 2) & 1;
        int reg  = (b & 3) + ((b >> 3) << 2);
        base[reg * 64 + lane_lo + (q << 5)] = acc[b] + bias;
    }
}

// =====================================================================
// K_prep3: w_hh -> MFMA B-fragment shards (unchanged)
// =====================================================================
__global__ __launch_bounds__(256) void k_prep3(const float* __restrict__ whh_f,
                                               const float* __restrict__ whh_r,
                                               u16* __restrict__ wpk3) {
    const int gid  = blockIdx.x * 256 + threadIdx.x;    // [0, 524288)
    const int j    = gid & 7;
    const int lane = (gid >> 3) & 63;
    const int kt   = (gid >> 9) & 15;
    const int nt   = (gid >> 13) & 7;
    const int js   = (gid >> 16) & 3;
    const int dir  = (gid >> 18) & 1;
    const int n_local = nt * 32 + (lane & 31);
    const int jjl  = n_local >> 2;
    const int gate = n_local & 3;
    const int k    = kt * 16 + (lane >> 5) * 8 + j;
    const int row  = gate * 256 + js * 64 + jjl;
    const float* whh = dir ? whh_r : whh_f;
    wpk3[gid] = f2bf(whh[(size_t)row * 256 + k]);
}

// k_init: zero all 8192 h-exchange records (2 dir x 2 parity x 2048)
__global__ __launch_bounds__(256) void k_init(v4u* __restrict__ hxrec) {
    const int id = blockIdx.x * 256 + threadIdx.x;
    v4u z; z[0] = 0u; z[1] = 0u; z[2] = 0u; z[3] = 0u;
    hxrec[id] = z;
}

// =====================================================================
// K3 v17 = R18's proven v13 (550.2us, absmax 0.0117) with ONE change:
// the consumer spin is 2-deep software-pipelined. Old: each poll = 3
// loads + vmcnt(0) -> one probe per IC round trip (~0.4us), and data
// landing mid-poll waits a full extra period. New: two poll sets A/B
// alternate with vmcnt(3) (waits only the OLDER set) -> probe cadence
// halves. WAIT3's "+v" operands pin register reads after the wait;
// DRAIN() prevents late-landing loads from clobbering reused registers.
// Numerics byte-identical (spin is data-neutral).
// =====================================================================
__global__ __launch_bounds__(512) void k_lstm3(const u16* __restrict__ wpk3,
                                               const float* __restrict__ xgF,
                                               u32* __restrict__ hxrec,
                                               float* __restrict__ hseq) {
    __shared__ u32   hbuf[32 * 132];          // h as bf16-pairs, row stride 132 dw
    __shared__ float slab[8 * 32 * 36];       // per-wave 32x36 f32 transpose slices
    const int dir = blockIdx.x >> 2;
    const int js  = blockIdx.x & 3;
    const int tid = threadIdx.x;
    const int w   = tid >> 6;                 // n-tile 0..7
    const int l   = tid & 63;
    const int m   = l & 31;
    const int q   = l >> 5;

    v8s Bf[16];
    {
        const u16* wb = wpk3 + ((((size_t)dir * 4 + js) * 8 + w) * 16) * 512 + (size_t)l * 8;
#pragma unroll
        for (int kt = 0; kt < 16; ++kt) Bf[kt] = *(const v8s*)(wb + kt * 512);
    }

    // EW ownership (wave-local): lane l -> batch bl, j-pair jp; handles
    // hidden j_global = js*64 + 8w + 4*jp + c, c=0..3
    const int jp = l & 1;
    const int bl = l >> 1;
    float cst[4], hval[4];
#pragma unroll
    for (int c = 0; c < 4; ++c) { cst[c] = 0.0f; hval[c] = 0.0f; }

    float* hout = hseq + (size_t)dir * 64 * 32 * 256;
    u32* hx_d   = hxrec + (size_t)dir * 2 * 2048 * 4;   // u32 units
    const u32* hx0 = hx_d;                    // parity-0 slot
    const u32* hx1 = hx_d + 2048 * 4;         // parity-1 slot

    // consumer record offsets (R13-identical): 48 peer q64-slots x 32 b
    int roff[3], hoff[3];
#pragma unroll
    for (int i = 0; i < 3; ++i) {
        int flat = i * 512 + tid;
        int b    = flat / 48;
        int r    = flat - b * 48;
        int q64  = r + (r >= js * 16 ? 16 : 0);
        roff[i]  = (b * 64 + q64) * 4;
        hoff[i]  = b * 132 + q64 * 2;
    }
    // producer slot: (batch bl, q64 = js*16 + 2w + jp)
    const int woff = (bl * 64 + js * 16 + 2 * w + jp) * 4;
    const int hown = bl * 132 + (js * 16 + 2 * w + jp) * 2;

    float* sl = &slab[w * 32 * 36];

    // prefetch xg for s=0
    float xcur[16];
    {
        const int t0 = dir ? 63 : 0;
        const float* xb = xgF + (((size_t)(dir * 64 + t0) * 32) + js * 8 + w) * 1024 + l;
#pragma unroll
        for (int r = 0; r < 16; ++r) xcur[r] = xb[r * 64];
    }

    for (int s = 0; s < 64; ++s) {
        v16f acc;
#pragma unroll
        for (int r = 0; r < 16; ++r) acc[r] = xcur[r];
        if (s < 63) {                          // prefetch next step's xg
            const int tn = dir ? (62 - s) : (s + 1);
            const float* xb = xgF + (((size_t)(dir * 64 + tn) * 32) + js * 8 + w) * 1024 + l;
#pragma unroll
            for (int r = 0; r < 16; ++r) xcur[r] = xb[r * 64];
        }

        if (s > 0) {
            // own pack (hval of step s-1)
            u64 pk = (u64)f2bf(hval[0]) | ((u64)f2bf(hval[1]) << 16)
                   | ((u64)f2bf(hval[2]) << 32) | ((u64)f2bf(hval[3]) << 48);
            *(u64*)&hbuf[hown] = pk;
            // 2-deep pipelined spin for 3 peer records (tag == s)
            const u32* hxs = (s & 1) ? hx1 : hx0;
            const u32* p0 = hxs + roff[0];
            const u32* p1 = hxs + roff[1];
            const u32* p2 = hxs + roff[2];
            const u32 ts = (u32)s;
            v4u a0, a1, a2, b0, b1, b2;
            LD3NW(a0, a1, a2, p0, p1, p2);
            int useA = 1;
            u32 guard = 0;
            for (;;) {
                LD3NW(b0, b1, b2, p0, p1, p2);
                WAIT3(a0, a1, a2);            // set A landed (vmcnt<=3)
                if (a0[2] == ts && a1[2] == ts && a2[2] == ts) { useA = 1; break; }
                if (++guard > (1u << 21)) { useA = 1; break; }
                LD3NW(a0, a1, a2, p0, p1, p2);
                WAIT3(b0, b1, b2);            // set B landed
                if (b0[2] == ts && b1[2] == ts && b2[2] == ts) { useA = 0; break; }
                if (++guard > (1u << 21)) { useA = 0; break; }
            }
            DRAIN();                          // retire stragglers before regs reused
            v4u r0 = useA ? a0 : b0;
            v4u r1 = useA ? a1 : b1;
            v4u r2 = useA ? a2 : b2;
            *(u64*)&hbuf[hoff[0]] = (u64)r0[0] | ((u64)r0[1] << 32);
            *(u64*)&hbuf[hoff[1]] = (u64)r1[0] | ((u64)r1[1] << 32);
            *(u64*)&hbuf[hoff[2]] = (u64)r2[0] | ((u64)r2[1] << 32);
        } else {
            for (int i = tid; i < 32 * 132; i += 512) hbuf[i] = 0u;
        }
        __syncthreads();                      // A: hbuf(s) ready

        v8s af[16];
#pragma unroll
        for (int kt = 0; kt < 16; ++kt)
            af[kt] = *(const v8s*)&hbuf[m * 132 + kt * 8 + q * 4];
        __syncthreads();                      // B: hbuf free for s+1

        // single dependent chain, R13's exact kt order -> bit-identical
#pragma unroll
        for (int kt = 0; kt < 16; ++kt)
            acc = __builtin_amdgcn_mfma_f32_32x32x16_bf16(af[kt], Bf[kt], acc, 0, 0, 0);

        // per-wave transpose: C[row=batch][col=m] -> (bl, gate quads)
#pragma unroll
        for (int r = 0; r < 16; ++r) {
            int row = (r & 3) + 8 * (r >> 2) + 4 * q;
            sl[row * 36 + m] = acc[r];
        }
        // wave-local W->R ordering: compiler inserts lgkmcnt (same buffer)
#pragma unroll
        for (int c = 0; c < 4; ++c) {
            float4 gv = *(const float4*)&sl[bl * 36 + jp * 16 + c * 4];
            float i_ = sigf(gv.x), f_ = sigf(gv.y);
            float g_ = tanhfast(gv.z), o_ = sigf(gv.w);
            cst[c]  = f_ * cst[c] + i_ * g_;
            hval[c] = o_ * tanhfast(cst[c]);
        }

        {
            const int t = dir ? (63 - s) : s;
            u64 pk = (u64)f2bf(hval[0]) | ((u64)f2bf(hval[1]) << 16)
                   | ((u64)f2bf(hval[2]) << 32) | ((u64)f2bf(hval[3]) << 48);
            v4u rec;
            rec[0] = (u32)pk;
            rec[1] = (u32)(pk >> 32);
            rec[2] = (u32)(s + 1);            // tag = step the record feeds
            rec[3] = 0u;
            u32* pw = (u32*)(((s & 1) ? hx0 : hx1) + woff);   // parity (s+1)&1
            ST16SYS(pw, rec);
            float4 hv4 = make_float4(hval[0], hval[1], hval[2], hval[3]);
            *(float4*)&hout[((size_t)t * 32 + bl) * 256 + js * 64 + 8 * w + 4 * jp] = hv4;
        }
    }
}

// =====================================================================
// K4: head (unchanged)
// =====================================================================
__global__ __launch_bounds__(256) void k_head(const float* __restrict__ hseq,
                                              const float* __restrict__ hw,
                                              const float* __restrict__ hb,
                                              float* __restrict__ out) {
    const int id = blockIdx.x * 256 + threadIdx.x;
    const int o  = id & 31;
    const int u  = id >> 5;
    const int b  = u >> 6, t = u & 63;
    const float* pf = hseq + ((size_t)t * 32 + b) * 256;
    const float* pr = hseq + (size_t)64 * 32 * 256 + ((size_t)t * 32 + b) * 256;
    const float* wo = hw + (size_t)o * 512;
    float acc = hb[o];
    for (int j = 0; j < 256; j += 4) {
        float4 wa = *(const float4*)(wo + j);
        float4 wb = *(const float4*)(wo + 256 + j);
        float4 fa = *(const float4*)(pf + j);
        float4 fb = *(const float4*)(pr + j);
        acc = fmaf(wa.x, fa.x, acc); acc = fmaf(wa.y, fa.y, acc);
        acc = fmaf(wa.z, fa.z, acc); acc = fmaf(wa.w, fa.w, acc);
        acc = fmaf(wb.x, fb.x, acc); acc = fmaf(wb.y, fb.y, acc);
        acc = fmaf(wb.z, fb.z, acc); acc = fmaf(wb.w, fb.w, acc);
    }
    out[id] = sigf(acc);
}

// =====================================================================
extern "C" void kernel_launch(void* const* d_in, const int* in_sizes, int n_in,
                              void* d_out, int out_size, void* d_ws, size_t ws_size,
                              hipStream_t stream) {
    const int*   dlg   = (const int*)d_in[0];
    const float* emb   = (const float*)d_in[1];
    const float* w3    = (const float*)d_in[2];  const float* b3    = (const float*)d_in[3];
    const float* w4    = (const float*)d_in[4];  const float* b4    = (const float*)d_in[5];
    const float* w5    = (const float*)d_in[6];  const float* b5    = (const float*)d_in[7];
    const float* wih_f = (const float*)d_in[8];  const float* whh_f = (const float*)d_in[9];
    const float* bih_f = (const float*)d_in[10]; const float* bhh_f = (const float*)d_in[11];
    const float* wih_r = (const float*)d_in[12]; const float* whh_r = (const float*)d_in[13];
    const float* bih_r = (const float*)d_in[14]; const float* bhh_r = (const float*)d_in[15];
    const float* hw    = (const float*)d_in[16]; const float* hb    = (const float*)d_in[17];
    float* out = (float*)d_out;

    float* f     = (float*)d_ws;
    float* feat  = f;                         // 614400
    float* xgF   = f + 614400;                // 4194304
    float* hseq  = f + 4808704;               // 1048576
    u16*   wkr   = (u16*)(f + 5857280);       // 466944 u16
    u16*   wpk3  = (u16*)(f + 6090752);       // 524288 u16
    u32*   hxrec = (u32*)(f + 6352896);       // 8192 records x 16B
    // total ~25.5 MB

    hipLaunchKernelGGL(k_init, dim3(32), dim3(256), 0, stream, (v4u*)hxrec);
    hipLaunchKernelGGL(k_cprep, dim3(WKR_TOT / 256), dim3(256), 0, stream,
                       w3, w4, w5, wkr);
    hipLaunchKernelGGL(k_prep3, dim3(2048), dim3(256), 0, stream,
                       whh_f, whh_r, wpk3);
    hipLaunchKernelGGL(k_conv_mfma, dim3(1024), dim3(384), 0, stream,
                       dlg, emb, wkr, b3, b4, b5, feat);
    hipLaunchKernelGGL(k_xg, dim3(512), dim3(256), 0, stream,
                       feat, wih_f, bih_f, bhh_f, wih_r, bih_r, bhh_r, xgF);
    hipLaunchKernelGGL(k_lstm3, dim3(8), dim3(512), 0, stream,
                       wpk3, xgF, hxrec, hseq);
    hipLaunchKernelGGL(k_head, dim3(256), dim3(256), 0, stream,
                       hseq, hw, hb, out);
}

// Round 12
// 547.496 us; speedup vs baseline: 1.2371x; 1.0479x over previous
//
#include <hip/hip_runtime.h>
#include <math.h>

typedef unsigned short u16;
typedef unsigned int   u32;
typedef unsigned long long u64;
typedef float  v16f __attribute__((ext_vector_type(16)));
typedef short  v8s  __attribute__((ext_vector_type(8)));
typedef unsigned int v4u __attribute__((ext_vector_type(4)));

__device__ __forceinline__ float sigf(float x) { return 1.0f / (1.0f + __expf(-x)); }
__device__ __forceinline__ float tanhfast(float x) { return 2.0f / (1.0f + __expf(-2.0f * x)) - 1.0f; }
__device__ __forceinline__ u16 f2bf(float f) {
    u32 x = __float_as_uint(f);
    u32 r = (x + 0x7fffu + ((x >> 16) & 1u)) >> 16;   // RNE
    return (u16)r;
}

// Agent-scope (sc1) 16B record ops (R13-proven): coherence point = IC.
#define LD3SYS(v0, v1, v2, p0, p1, p2)                                        \
    asm volatile("global_load_dwordx4 %0, %3, off sc1\n\t"                    \
                 "global_load_dwordx4 %1, %4, off sc1\n\t"                    \
                 "global_load_dwordx4 %2, %5, off sc1\n\t"                    \
                 "s_waitcnt vmcnt(0)"                                         \
                 : "=&v"(v0), "=&v"(v1), "=&v"(v2)                            \
                 : "v"(p0), "v"(p1), "v"(p2)                                  \
                 : "memory")

#define ST16SYS(p, v)                                                         \
    asm volatile("global_store_dwordx4 %0, %1, off sc1"                       \
                 :: "v"(p), "v"(v) : "memory")

// ---------------------------------------------------------------------
// Conv-as-MFMA constants (verified R4)
// ---------------------------------------------------------------------
#define KE        19
#define SLAB      2048
#define G0_OFF    0
#define G1_OFF    (3 * KE * SLAB)
#define G2_OFF    (7 * KE * SLAB)
#define WKR_TOT   (12 * KE * SLAB)
#define XSTR      312

// k_cprep: conv-weight repack; first 32 blocks also zero the 8192
// h-exchange records (k_init merged here -> one fewer launch).
__global__ __launch_bounds__(256) void k_cprep(const float* __restrict__ w3,
                                               const float* __restrict__ w4,
                                               const float* __restrict__ w5,
                                               u16* __restrict__ wkr,
                                               v4u* __restrict__ hxrec) {
    if (blockIdx.x < 32) {
        v4u z; z[0] = 0u; z[1] = 0u; z[2] = 0u; z[3] = 0u;
        hxrec[blockIdx.x * 256 + threadIdx.x] = z;
    }
    const int gid = blockIdx.x * 256 + threadIdx.x;
    int g, rem;
    if (gid < G1_OFF)      { g = 0; rem = gid; }
    else if (gid < G2_OFF) { g = 1; rem = gid - G1_OFF; }
    else                   { g = 2; rem = gid - G2_OFF; }
    const int fs = 3 + g;
    const int j  = rem & 7;
    const int q  = (rem >> 3) & 1;
    const int f  = (rem >> 4) & 127;
    const int t  = rem >> 11;
    const int ke = t % KE;
    const int kk = t / KE;
    const int e  = ke * 16 + q * 8 + j;
    float v = 0.0f;
    if (f < 100 && e < 300) {
        const float* w = (g == 0) ? w3 : (g == 1) ? w4 : w5;
        v = w[((size_t)f * 300 + e) * fs + kk];
    }
    wkr[gid] = f2bf(v);
}

// =====================================================================
// K1: conv via MFMA (unchanged, R11-proven)
// =====================================================================
__global__ __launch_bounds__(384) void k_conv_mfma(const int* __restrict__ dlg,
                                                   const float* __restrict__ emb,
                                                   const u16* __restrict__ wkr,
                                                   const float* __restrict__ b3,
                                                   const float* __restrict__ b4,
                                                   const float* __restrict__ b5,
                                                   float* __restrict__ feat) {
    __shared__ u16 xT[104 * XSTR];
    __shared__ int toks[96];
    const int u2  = blockIdx.x;
    const int tid = threadIdx.x;
    if (tid < 96) toks[tid] = dlg[u2 * 96 + tid];
    __syncthreads();
    for (int i = tid; i < 96 * 75; i += 384) {
        int t  = i / 75;
        int e4 = i - t * 75;
        int utt = (t >= 48);
        int row = utt * 52 + (t - utt * 48);
        float4 v = *(const float4*)(emb + (size_t)toks[t] * 300 + e4 * 4);
        uint2 o;
        o.x = (u32)f2bf(v.x) | ((u32)f2bf(v.y) << 16);
        o.y = (u32)f2bf(v.z) | ((u32)f2bf(v.w) << 16);
        *(uint2*)&xT[row * XSTR + e4 * 4] = o;
    }
    for (int i = tid; i < 8 * (XSTR / 2); i += 384) {
        int r = i / (XSTR / 2);
        int c = i - r * (XSTR / 2);
        int row = (r < 4) ? (48 + r) : (96 + r - 4);
        *(u32*)&xT[row * XSTR + c * 2] = 0;
    }
    __syncthreads();

    const int wv   = tid >> 6;
    const int lane = tid & 63;
    const int m    = lane & 31;
    const int q    = lane >> 5;

    int abase[3];
#pragma unroll
    for (int mt = 0; mt < 3; ++mt) {
        int r = mt * 32 + m;
        int utt = (r >= 48);
        int p = r - utt * 48;
        abase[mt] = (utt * 52 + p) * XSTR + q * 8;
    }

    int gA, ntA, gB, ntB, kkA, kkB;
    if (wv < 4) { gA = 0; ntA = wv; gB = 2; ntB = wv; kkA = 3; kkB = 5; }
    else        { gA = 1; ntA = (wv - 4) * 2; gB = 1; ntB = ntA + 1; kkA = 4; kkB = 4; }
    const int goffA = (gA == 0) ? G0_OFF : (gA == 1) ? G1_OFF : G2_OFF;
    const int goffB = (gB == 0) ? G0_OFF : (gB == 1) ? G1_OFF : G2_OFF;
    const u16* wA = wkr + goffA + ((ntA * 32 + m) * 2 + q) * 8;
    const u16* wB = wkr + goffB + ((ntB * 32 + m) * 2 + q) * 8;

    v16f accA[3], accB[3];
#pragma unroll
    for (int mt = 0; mt < 3; ++mt) {
#pragma unroll
        for (int r = 0; r < 16; ++r) { accA[mt][r] = 0.0f; accB[mt][r] = 0.0f; }
    }

    const int kmin = (kkA < kkB) ? kkA : kkB;   // waves0-3: 3, waves4-5: 4
    const u16* pA = wA;
    const u16* pB = wB;
    v8s bfA = *(const v8s*)pA;
    v8s bfB = *(const v8s*)pB;
    for (int kk = 0; kk < kmin; ++kk) {
        const int xshift = kk * XSTR;
        for (int ke = 0; ke < KE; ++ke) {
            v8s cA = bfA, cB = bfB;
            pA += SLAB; pB += SLAB;
            bfA = *(const v8s*)pA;             // prefetch (harmless overread at end)
            bfB = *(const v8s*)pB;
            const int xcol = xshift + ke * 16;
#pragma unroll
            for (int mt = 0; mt < 3; ++mt) {
                v8s af = *(const v8s*)&xT[abase[mt] + xcol];
                accA[mt] = __builtin_amdgcn_mfma_f32_32x32x16_bf16(af, cA, accA[mt], 0, 0, 0);
                accB[mt] = __builtin_amdgcn_mfma_f32_32x32x16_bf16(af, cB, accB[mt], 0, 0, 0);
            }
        }
    }
    for (int kk = kmin; kk < kkB; ++kk) {
        const int xshift = kk * XSTR;
        for (int ke = 0; ke < KE; ++ke) {
            v8s cB = bfB;
            pB += SLAB;
            bfB = *(const v8s*)pB;
            const int xcol = xshift + ke * 16;
#pragma unroll
            for (int mt = 0; mt < 3; ++mt) {
                v8s af = *(const v8s*)&xT[abase[mt] + xcol];
                accB[mt] = __builtin_amdgcn_mfma_f32_32x32x16_bf16(af, cB, accB[mt], 0, 0, 0);
            }
        }
    }

    const int PP[3] = {46, 45, 44};
#pragma unroll
    for (int which = 0; which < 2; ++which) {
        const int g  = which ? gB : gA;
        const int nt = which ? ntB : ntA;
        const v16f* acc = which ? accB : accA;
        const float* bg = (g == 0) ? b3 : (g == 1) ? b4 : b5;
        const int f = nt * 32 + m;
        const float bias = (f < 100) ? bg[f] : 0.0f;
        const int Pg = PP[g];
        float v0 = -1e30f, v1 = -1e30f;
#pragma unroll
        for (int mt = 0; mt < 3; ++mt) {
#pragma unroll
            for (int reg = 0; reg < 16; ++reg) {
                int row = (reg & 3) + 8 * (reg >> 2) + 4 * q;
                int r = mt * 32 + row;
                int utt = (r >= 48);
                int p = r - utt * 48;
                if (p < Pg) {
                    float val = acc[mt][reg] + bias;
                    if (utt) v1 = fmaxf(v1, val); else v0 = fmaxf(v0, val);
                }
            }
        }
        v0 = fmaxf(v0, __shfl_xor(v0, 32, 64));
        v1 = fmaxf(v1, __shfl_xor(v1, 32, 64));
        if (q == 0 && f < 100) {
            feat[((size_t)(u2 * 2 + 0)) * 300 + g * 100 + f] = fmaxf(0.0f, v0);
            feat[((size_t)(u2 * 2 + 1)) * 300 + g * 100 + f] = fmaxf(0.0f, v1);
        }
    }
}

// =====================================================================
// K2: xg GEMM; output in MFMA C-fragment order (unchanged)
// =====================================================================
__global__ __launch_bounds__(256) void k_xg(const float* __restrict__ feat,
                                            const float* __restrict__ wih_f, const float* __restrict__ bih_f,
                                            const float* __restrict__ bhh_f,
                                            const float* __restrict__ wih_r, const float* __restrict__ bih_r,
                                            const float* __restrict__ bhh_r,
                                            float* __restrict__ xgF) {
    __shared__ float fls[300 * 36];
    const int bx  = blockIdx.x;
    const int dir = bx >> 8;
    const int t   = (bx >> 2) & 63;
    const int gc  = bx & 3;
    const int tid = threadIdx.x;
    for (int i = tid; i < 32 * 300; i += 256) {
        int b = i / 300;
        int d = i - b * 300;
        fls[d * 36 + b] = feat[((size_t)b * 64 + t) * 300 + d];
    }
    __syncthreads();
    const int g = gc * 256 + tid;
    const float* wih = dir ? wih_r : wih_f;
    const float* bih = dir ? bih_r : bih_f;
    const float* bhh = dir ? bhh_r : bhh_f;
    const float* wr  = wih + (size_t)g * 300;
    const float bias = bih[g] + bhh[g];
    float acc[32];
#pragma unroll
    for (int b = 0; b < 32; ++b) acc[b] = 0.0f;
    for (int d = 0; d < 300; d += 4) {
        float4 wv = *(const float4*)(wr + d);
#pragma unroll
        for (int j = 0; j < 4; ++j) {
            float w = (j == 0) ? wv.x : (j == 1) ? wv.y : (j == 2) ? wv.z : wv.w;
            const float* r = &fls[(d + j) * 36];
#pragma unroll
            for (int bq = 0; bq < 8; ++bq) {
                float4 x = *(const float4*)(r + bq * 4);
                acc[bq * 4 + 0] = fmaf(w, x.x, acc[bq * 4 + 0]);
                acc[bq * 4 + 1] = fmaf(w, x.y, acc[bq * 4 + 1]);
                acc[bq * 4 + 2] = fmaf(w, x.z, acc[bq * 4 + 2]);
                acc[bq * 4 + 3] = fmaf(w, x.w, acc[bq * 4 + 3]);
            }
        }
    }
    const int jj      = tid;
    const int js      = jj >> 6;
    const int n_local = ((jj & 63) << 2) | gc;
    const int nt      = n_local >> 5;
    const int lane_lo = n_local & 31;
    float* base = xgF + (((size_t)(dir * 64 + t) * 32) + js * 8 + nt) * 1024;
#pragma unroll
    for (int b = 0; b < 32; ++b) {
        int q    = (b >> 2) & 1;
        int reg  = (b & 3) + ((b >> 3) << 2);
        base[reg * 64 + lane_lo + (q << 5)] = acc[b] + bias;
    }
}

// =====================================================================
// K_prep3: w_hh -> MFMA B-fragment shards (unchanged)
// =====================================================================
__global__ __launch_bounds__(256) void k_prep3(const float* __restrict__ whh_f,
                                               const float* __restrict__ whh_r,
                                               u16* __restrict__ wpk3) {
    const int gid  = blockIdx.x * 256 + threadIdx.x;    // [0, 524288)
    const int j    = gid & 7;
    const int lane = (gid >> 3) & 63;
    const int kt   = (gid >> 9) & 15;
    const int nt   = (gid >> 13) & 7;
    const int js   = (gid >> 16) & 3;
    const int dir  = (gid >> 18) & 1;
    const int n_local = nt * 32 + (lane & 31);
    const int jjl  = n_local >> 2;
    const int gate = n_local & 3;
    const int k    = kt * 16 + (lane >> 5) * 8 + j;
    const int row  = gate * 256 + js * 64 + jjl;
    const float* whh = dir ? whh_r : whh_f;
    wpk3[gid] = f2bf(whh[(size_t)row * 256 + k]);
}

// =====================================================================
// K3 v18 = R18's proven v13 (550.2us, absmax 0.0117) with the one
// remaining provably-safe cut: hbuf double-buffered on s&1 -> barrier B
// removed (1 barrier/step instead of 2). Invariant: step s+2's writes to
// hbuf[s&1] occur after barrier A(s+1), and every thread's step-s af
// reads complete before it reaches barrier A(s+1) — the classic
// 2-buffer/1-barrier pattern. Numerics bit-identical to R18.
// =====================================================================
__global__ __launch_bounds__(512) void k_lstm3(const u16* __restrict__ wpk3,
                                               const float* __restrict__ xgF,
                                               u32* __restrict__ hxrec,
                                               float* __restrict__ hseq) {
    __shared__ u32   hbuf[2][32 * 132];       // double-buffered h (bf16 pairs)
    __shared__ float slab[8 * 32 * 36];       // per-wave 32x36 f32 transpose slices
    const int dir = blockIdx.x >> 2;
    const int js  = blockIdx.x & 3;
    const int tid = threadIdx.x;
    const int w   = tid >> 6;                 // n-tile 0..7
    const int l   = tid & 63;
    const int m   = l & 31;
    const int q   = l >> 5;

    v8s Bf[16];
    {
        const u16* wb = wpk3 + ((((size_t)dir * 4 + js) * 8 + w) * 16) * 512 + (size_t)l * 8;
#pragma unroll
        for (int kt = 0; kt < 16; ++kt) Bf[kt] = *(const v8s*)(wb + kt * 512);
    }

    // EW ownership (wave-local): lane l -> batch bl, j-pair jp; handles
    // hidden j_global = js*64 + 8w + 4*jp + c, c=0..3
    const int jp = l & 1;
    const int bl = l >> 1;
    float cst[4], hval[4];
#pragma unroll
    for (int c = 0; c < 4; ++c) { cst[c] = 0.0f; hval[c] = 0.0f; }

    float* hout = hseq + (size_t)dir * 64 * 32 * 256;
    u32* hx_d   = hxrec + (size_t)dir * 2 * 2048 * 4;   // u32 units
    const u32* hx0 = hx_d;                    // parity-0 slot
    const u32* hx1 = hx_d + 2048 * 4;         // parity-1 slot

    // consumer record offsets (R13-identical): 48 peer q64-slots x 32 b
    int roff[3], hoff[3];
#pragma unroll
    for (int i = 0; i < 3; ++i) {
        int flat = i * 512 + tid;
        int b    = flat / 48;
        int r    = flat - b * 48;
        int q64  = r + (r >= js * 16 ? 16 : 0);
        roff[i]  = (b * 64 + q64) * 4;
        hoff[i]  = b * 132 + q64 * 2;
    }
    // producer slot: (batch bl, q64 = js*16 + 2w + jp)
    const int woff = (bl * 64 + js * 16 + 2 * w + jp) * 4;
    const int hown = bl * 132 + (js * 16 + 2 * w + jp) * 2;

    float* sl = &slab[w * 32 * 36];

    // prefetch xg for s=0
    float xcur[16];
    {
        const int t0 = dir ? 63 : 0;
        const float* xb = xgF + (((size_t)(dir * 64 + t0) * 32) + js * 8 + w) * 1024 + l;
#pragma unroll
        for (int r = 0; r < 16; ++r) xcur[r] = xb[r * 64];
    }

    for (int s = 0; s < 64; ++s) {
        u32* hb = hbuf[s & 1];
        v16f acc;
#pragma unroll
        for (int r = 0; r < 16; ++r) acc[r] = xcur[r];
        if (s < 63) {                          // prefetch next step's xg
            const int tn = dir ? (62 - s) : (s + 1);
            const float* xb = xgF + (((size_t)(dir * 64 + tn) * 32) + js * 8 + w) * 1024 + l;
#pragma unroll
            for (int r = 0; r < 16; ++r) xcur[r] = xb[r * 64];
        }

        if (s > 0) {
            // own pack (hval of step s-1)
            u64 pk = (u64)f2bf(hval[0]) | ((u64)f2bf(hval[1]) << 16)
                   | ((u64)f2bf(hval[2]) << 32) | ((u64)f2bf(hval[3]) << 48);
            *(u64*)&hb[hown] = pk;
            // spin for 3 peer records (tag == s)
            const u32* hxs = (s & 1) ? hx1 : hx0;
            const u32* p0 = hxs + roff[0];
            const u32* p1 = hxs + roff[1];
            const u32* p2 = hxs + roff[2];
            v4u v0, v1, v2;
            LD3SYS(v0, v1, v2, p0, p1, p2);
            const u32 ts = (u32)s;
            u32 guard = 0;
            while (v0[2] != ts || v1[2] != ts || v2[2] != ts) {
                if (++guard > (1u << 22)) break;
                LD3SYS(v0, v1, v2, p0, p1, p2);
            }
            *(u64*)&hb[hoff[0]] = (u64)v0[0] | ((u64)v0[1] << 32);
            *(u64*)&hb[hoff[1]] = (u64)v1[0] | ((u64)v1[1] << 32);
            *(u64*)&hb[hoff[2]] = (u64)v2[0] | ((u64)v2[1] << 32);
        } else {
            for (int i = tid; i < 32 * 132; i += 512) hb[i] = 0u;
        }
        __syncthreads();                      // barrier A: hbuf[s&1] ready

        v8s af[16];
#pragma unroll
        for (int kt = 0; kt < 16; ++kt)
            af[kt] = *(const v8s*)&hb[m * 132 + kt * 8 + q * 4];
        // (no barrier B: next step writes hbuf[(s+1)&1]; step s+2's writes
        //  to hbuf[s&1] are fenced by barrier A(s+1))

        // single dependent chain, R13's exact kt order -> bit-identical
#pragma unroll
        for (int kt = 0; kt < 16; ++kt)
            acc = __builtin_amdgcn_mfma_f32_32x32x16_bf16(af[kt], Bf[kt], acc, 0, 0, 0);

        // per-wave transpose: C[row=batch][col=m] -> (bl, gate quads)
#pragma unroll
        for (int r = 0; r < 16; ++r) {
            int row = (r & 3) + 8 * (r >> 2) + 4 * q;
            sl[row * 36 + m] = acc[r];
        }
        // wave-local W->R ordering: compiler inserts lgkmcnt (same buffer)
#pragma unroll
        for (int c = 0; c < 4; ++c) {
            float4 gv = *(const float4*)&sl[bl * 36 + jp * 16 + c * 4];
            float i_ = sigf(gv.x), f_ = sigf(gv.y);
            float g_ = tanhfast(gv.z), o_ = sigf(gv.w);
            cst[c]  = f_ * cst[c] + i_ * g_;
            hval[c] = o_ * tanhfast(cst[c]);
        }

        {
            const int t = dir ? (63 - s) : s;
            u64 pk = (u64)f2bf(hval[0]) | ((u64)f2bf(hval[1]) << 16)
                   | ((u64)f2bf(hval[2]) << 32) | ((u64)f2bf(hval[3]) << 48);
            v4u rec;
            rec[0] = (u32)pk;
            rec[1] = (u32)(pk >> 32);
            rec[2] = (u32)(s + 1);            // tag = step the record feeds
            rec[3] = 0u;
            u32* pw = (u32*)(((s & 1) ? hx0 : hx1) + woff);   // parity (s+1)&1
            ST16SYS(pw, rec);
            float4 hv4 = make_float4(hval[0], hval[1], hval[2], hval[3]);
            *(float4*)&hout[((size_t)t * 32 + bl) * 256 + js * 64 + 8 * w + 4 * jp] = hv4;
        }
    }
}

// =====================================================================
// K4: head (unchanged)
// =====================================================================
__global__ __launch_bounds__(256) void k_head(const float* __restrict__ hseq,
                                              const float* __restrict__ hw,
                                              const float* __restrict__ hb,
                                              float* __restrict__ out) {
    const int id = blockIdx.x * 256 + threadIdx.x;
    const int o  = id & 31;
    const int u  = id >> 5;
    const int b  = u >> 6, t = u & 63;
    const float* pf = hseq + ((size_t)t * 32 + b) * 256;
    const float* pr = hseq + (size_t)64 * 32 * 256 + ((size_t)t * 32 + b) * 256;
    const float* wo = hw + (size_t)o * 512;
    float acc = hb[o];
    for (int j = 0; j < 256; j += 4) {
        float4 wa = *(const float4*)(wo + j);
        float4 wb = *(const float4*)(wo + 256 + j);
        float4 fa = *(const float4*)(pf + j);
        float4 fb = *(const float4*)(pr + j);
        acc = fmaf(wa.x, fa.x, acc); acc = fmaf(wa.y, fa.y, acc);
        acc = fmaf(wa.z, fa.z, acc); acc = fmaf(wa.w, fa.w, acc);
        acc = fmaf(wb.x, fb.x, acc); acc = fmaf(wb.y, fb.y, acc);
        acc = fmaf(wb.z, fb.z, acc); acc = fmaf(wb.w, fb.w, acc);
    }
    out[id] = sigf(acc);
}

// =====================================================================
extern "C" void kernel_launch(void* const* d_in, const int* in_sizes, int n_in,
                              void* d_out, int out_size, void* d_ws, size_t ws_size,
                              hipStream_t stream) {
    const int*   dlg   = (const int*)d_in[0];
    const float* emb   = (const float*)d_in[1];
    const float* w3    = (const float*)d_in[2];  const float* b3    = (const float*)d_in[3];
    const float* w4    = (const float*)d_in[4];  const float* b4    = (const float*)d_in[5];
    const float* w5    = (const float*)d_in[6];  const float* b5    = (const float*)d_in[7];
    const float* wih_f = (const float*)d_in[8];  const float* whh_f = (const float*)d_in[9];
    const float* bih_f = (const float*)d_in[10]; const float* bhh_f = (const float*)d_in[11];
    const float* wih_r = (const float*)d_in[12]; const float* whh_r = (const float*)d_in[13];
    const float* bih_r = (const float*)d_in[14]; const float* bhh_r = (const float*)d_in[15];
    const float* hw    = (const float*)d_in[16]; const float* hb    = (const float*)d_in[17];
    float* out = (float*)d_out;

    float* f     = (float*)d_ws;
    float* feat  = f;                         // 614400
    float* xgF   = f + 614400;                // 4194304
    float* hseq  = f + 4808704;               // 1048576
    u16*   wkr   = (u16*)(f + 5857280);       // 466944 u16
    u16*   wpk3  = (u16*)(f + 6090752);       // 524288 u16
    u32*   hxrec = (u32*)(f + 6352896);       // 8192 records x 16B
    // total ~25.5 MB

    hipLaunchKernelGGL(k_cprep, dim3(WKR_TOT / 256), dim3(256), 0, stream,
                       w3, w4, w5, wkr, (v4u*)hxrec);
    hipLaunchKernelGGL(k_prep3, dim3(2048), dim3(256), 0, stream,
                       whh_f, whh_r, wpk3);
    hipLaunchKernelGGL(k_conv_mfma, dim3(1024), dim3(384), 0, stream,
                       dlg, emb, wkr, b3, b4, b5, feat);
    hipLaunchKernelGGL(k_xg, dim3(512), dim3(256), 0, stream,
                       feat, wih_f, bih_f, bhh_f, wih_r, bih_r, bhh_r, xgF);
    hipLaunchKernelGGL(k_lstm3, dim3(8), dim3(512), 0, stream,
                       wpk3, xgF, hxrec, hseq);
    hipLaunchKernelGGL(k_head, dim3(256), dim3(256), 0, stream,
                       hseq, hw, hb, out);
}

// Round 13
// 540.451 us; speedup vs baseline: 1.2532x; 1.0130x over previous
//
#include <hip/hip_runtime.h>
#include <math.h>

typedef unsigned short u16;
typedef unsigned int   u32;
typedef unsigned long long u64;
typedef float  v16f __attribute__((ext_vector_type(16)));
typedef short  v8s  __attribute__((ext_vector_type(8)));
typedef unsigned int v4u __attribute__((ext_vector_type(4)));

__device__ __forceinline__ float sigf(float x) { return 1.0f / (1.0f + __expf(-x)); }
__device__ __forceinline__ float tanhfast(float x) { return 2.0f / (1.0f + __expf(-2.0f * x)) - 1.0f; }
__device__ __forceinline__ u16 f2bf(float f) {
    u32 x = __float_as_uint(f);
    u32 r = (x + 0x7fffu + ((x >> 16) & 1u)) >> 16;   // RNE
    return (u16)r;
}

// Agent-scope (sc1) 16B record ops (R13-proven): coherence point = IC.
#define LD3SYS(v0, v1, v2, p0, p1, p2)                                        \
    asm volatile("global_load_dwordx4 %0, %3, off sc1\n\t"                    \
                 "global_load_dwordx4 %1, %4, off sc1\n\t"                    \
                 "global_load_dwordx4 %2, %5, off sc1\n\t"                    \
                 "s_waitcnt vmcnt(0)"                                         \
                 : "=&v"(v0), "=&v"(v1), "=&v"(v2)                            \
                 : "v"(p0), "v"(p1), "v"(p2)                                  \
                 : "memory")

#define ST16SYS(p, v)                                                         \
    asm volatile("global_store_dwordx4 %0, %1, off sc1"                       \
                 :: "v"(p), "v"(v) : "memory")

// ---------------------------------------------------------------------
// Conv-as-MFMA constants (verified R4)
// ---------------------------------------------------------------------
#define KE        19
#define SLAB      2048
#define G0_OFF    0
#define G1_OFF    (3 * KE * SLAB)
#define G2_OFF    (7 * KE * SLAB)
#define WKR_TOT   (12 * KE * SLAB)
#define XSTR      312
#define CPREP_NB  (WKR_TOT / 256)             // 1824 blocks for the conv repack

// =====================================================================
// K_prep (fused): blocks [0, CPREP_NB) do the conv-weight repack
// (k_cprep; first 32 also zero the h-exchange records); blocks
// [CPREP_NB, CPREP_NB+2048) do the w_hh repack (k_prep3). The two
// repacks are independent; fusing lets them run concurrently instead of
// serially on the single stream (G9 bans hipEvent* fork/join).
// Both bodies byte-identical to the proven kernels.
// =====================================================================
__global__ __launch_bounds__(256) void k_prep(const float* __restrict__ w3,
                                              const float* __restrict__ w4,
                                              const float* __restrict__ w5,
                                              u16* __restrict__ wkr,
                                              v4u* __restrict__ hxrec,
                                              const float* __restrict__ whh_f,
                                              const float* __restrict__ whh_r,
                                              u16* __restrict__ wpk3) {
    if (blockIdx.x < CPREP_NB) {
        // ---- conv-weight repack (k_cprep body) ----
        if (blockIdx.x < 32) {
            v4u z; z[0] = 0u; z[1] = 0u; z[2] = 0u; z[3] = 0u;
            hxrec[blockIdx.x * 256 + threadIdx.x] = z;
        }
        const int gid = blockIdx.x * 256 + threadIdx.x;
        int g, rem;
        if (gid < G1_OFF)      { g = 0; rem = gid; }
        else if (gid < G2_OFF) { g = 1; rem = gid - G1_OFF; }
        else                   { g = 2; rem = gid - G2_OFF; }
        const int fs = 3 + g;
        const int j  = rem & 7;
        const int q  = (rem >> 3) & 1;
        const int f  = (rem >> 4) & 127;
        const int t  = rem >> 11;
        const int ke = t % KE;
        const int kk = t / KE;
        const int e  = ke * 16 + q * 8 + j;
        float v = 0.0f;
        if (f < 100 && e < 300) {
            const float* w = (g == 0) ? w3 : (g == 1) ? w4 : w5;
            v = w[((size_t)f * 300 + e) * fs + kk];
        }
        wkr[gid] = f2bf(v);
    } else {
        // ---- w_hh repack (k_prep3 body) ----
        const int gid  = (blockIdx.x - CPREP_NB) * 256 + threadIdx.x;  // [0, 524288)
        const int j    = gid & 7;
        const int lane = (gid >> 3) & 63;
        const int kt   = (gid >> 9) & 15;
        const int nt   = (gid >> 13) & 7;
        const int js   = (gid >> 16) & 3;
        const int dir  = (gid >> 18) & 1;
        const int n_local = nt * 32 + (lane & 31);
        const int jjl  = n_local >> 2;
        const int gate = n_local & 3;
        const int k    = kt * 16 + (lane >> 5) * 8 + j;
        const int row  = gate * 256 + js * 64 + jjl;
        const float* whh = dir ? whh_r : whh_f;
        wpk3[gid] = f2bf(whh[(size_t)row * 256 + k]);
    }
}

// =====================================================================
// K1: conv via MFMA (unchanged, R11-proven)
// =====================================================================
__global__ __launch_bounds__(384) void k_conv_mfma(const int* __restrict__ dlg,
                                                   const float* __restrict__ emb,
                                                   const u16* __restrict__ wkr,
                                                   const float* __restrict__ b3,
                                                   const float* __restrict__ b4,
                                                   const float* __restrict__ b5,
                                                   float* __restrict__ feat) {
    __shared__ u16 xT[104 * XSTR];
    __shared__ int toks[96];
    const int u2  = blockIdx.x;
    const int tid = threadIdx.x;
    if (tid < 96) toks[tid] = dlg[u2 * 96 + tid];
    __syncthreads();
    for (int i = tid; i < 96 * 75; i += 384) {
        int t  = i / 75;
        int e4 = i - t * 75;
        int utt = (t >= 48);
        int row = utt * 52 + (t - utt * 48);
        float4 v = *(const float4*)(emb + (size_t)toks[t] * 300 + e4 * 4);
        uint2 o;
        o.x = (u32)f2bf(v.x) | ((u32)f2bf(v.y) << 16);
        o.y = (u32)f2bf(v.z) | ((u32)f2bf(v.w) << 16);
        *(uint2*)&xT[row * XSTR + e4 * 4] = o;
    }
    for (int i = tid; i < 8 * (XSTR / 2); i += 384) {
        int r = i / (XSTR / 2);
        int c = i - r * (XSTR / 2);
        int row = (r < 4) ? (48 + r) : (96 + r - 4);
        *(u32*)&xT[row * XSTR + c * 2] = 0;
    }
    __syncthreads();

    const int wv   = tid >> 6;
    const int lane = tid & 63;
    const int m    = lane & 31;
    const int q    = lane >> 5;

    int abase[3];
#pragma unroll
    for (int mt = 0; mt < 3; ++mt) {
        int r = mt * 32 + m;
        int utt = (r >= 48);
        int p = r - utt * 48;
        abase[mt] = (utt * 52 + p) * XSTR + q * 8;
    }

    int gA, ntA, gB, ntB, kkA, kkB;
    if (wv < 4) { gA = 0; ntA = wv; gB = 2; ntB = wv; kkA = 3; kkB = 5; }
    else        { gA = 1; ntA = (wv - 4) * 2; gB = 1; ntB = ntA + 1; kkA = 4; kkB = 4; }
    const int goffA = (gA == 0) ? G0_OFF : (gA == 1) ? G1_OFF : G2_OFF;
    const int goffB = (gB == 0) ? G0_OFF : (gB == 1) ? G1_OFF : G2_OFF;
    const u16* wA = wkr + goffA + ((ntA * 32 + m) * 2 + q) * 8;
    const u16* wB = wkr + goffB + ((ntB * 32 + m) * 2 + q) * 8;

    v16f accA[3], accB[3];
#pragma unroll
    for (int mt = 0; mt < 3; ++mt) {
#pragma unroll
        for (int r = 0; r < 16; ++r) { accA[mt][r] = 0.0f; accB[mt][r] = 0.0f; }
    }

    const int kmin = (kkA < kkB) ? kkA : kkB;   // waves0-3: 3, waves4-5: 4
    const u16* pA = wA;
    const u16* pB = wB;
    v8s bfA = *(const v8s*)pA;
    v8s bfB = *(const v8s*)pB;
    for (int kk = 0; kk < kmin; ++kk) {
        const int xshift = kk * XSTR;
        for (int ke = 0; ke < KE; ++ke) {
            v8s cA = bfA, cB = bfB;
            pA += SLAB; pB += SLAB;
            bfA = *(const v8s*)pA;             // prefetch (harmless overread at end)
            bfB = *(const v8s*)pB;
            const int xcol = xshift + ke * 16;
#pragma unroll
            for (int mt = 0; mt < 3; ++mt) {
                v8s af = *(const v8s*)&xT[abase[mt] + xcol];
                accA[mt] = __builtin_amdgcn_mfma_f32_32x32x16_bf16(af, cA, accA[mt], 0, 0, 0);
                accB[mt] = __builtin_amdgcn_mfma_f32_32x32x16_bf16(af, cB, accB[mt], 0, 0, 0);
            }
        }
    }
    for (int kk = kmin; kk < kkB; ++kk) {
        const int xshift = kk * XSTR;
        for (int ke = 0; ke < KE; ++ke) {
            v8s cB = bfB;
            pB += SLAB;
            bfB = *(const v8s*)pB;
            const int xcol = xshift + ke * 16;
#pragma unroll
            for (int mt = 0; mt < 3; ++mt) {
                v8s af = *(const v8s*)&xT[abase[mt] + xcol];
                accB[mt] = __builtin_amdgcn_mfma_f32_32x32x16_bf16(af, cB, accB[mt], 0, 0, 0);
            }
        }
    }

    const int PP[3] = {46, 45, 44};
#pragma unroll
    for (int which = 0; which < 2; ++which) {
        const int g  = which ? gB : gA;
        const int nt = which ? ntB : ntA;
        const v16f* acc = which ? accB : accA;
        const float* bg = (g == 0) ? b3 : (g == 1) ? b4 : b5;
        const int f = nt * 32 + m;
        const float bias = (f < 100) ? bg[f] : 0.0f;
        const int Pg = PP[g];
        float v0 = -1e30f, v1 = -1e30f;
#pragma unroll
        for (int mt = 0; mt < 3; ++mt) {
#pragma unroll
            for (int reg = 0; reg < 16; ++reg) {
                int row = (reg & 3) + 8 * (reg >> 2) + 4 * q;
                int r = mt * 32 + row;
                int utt = (r >= 48);
                int p = r - utt * 48;
                if (p < Pg) {
                    float val = acc[mt][reg] + bias;
                    if (utt) v1 = fmaxf(v1, val); else v0 = fmaxf(v0, val);
                }
            }
        }
        v0 = fmaxf(v0, __shfl_xor(v0, 32, 64));
        v1 = fmaxf(v1, __shfl_xor(v1, 32, 64));
        if (q == 0 && f < 100) {
            feat[((size_t)(u2 * 2 + 0)) * 300 + g * 100 + f] = fmaxf(0.0f, v0);
            feat[((size_t)(u2 * 2 + 1)) * 300 + g * 100 + f] = fmaxf(0.0f, v1);
        }
    }
}

// =====================================================================
// K2: xg GEMM; output in MFMA C-fragment order (unchanged)
// =====================================================================
__global__ __launch_bounds__(256) void k_xg(const float* __restrict__ feat,
                                            const float* __restrict__ wih_f, const float* __restrict__ bih_f,
                                            const float* __restrict__ bhh_f,
                                            const float* __restrict__ wih_r, const float* __restrict__ bih_r,
                                            const float* __restrict__ bhh_r,
                                            float* __restrict__ xgF) {
    __shared__ float fls[300 * 36];
    const int bx  = blockIdx.x;
    const int dir = bx >> 8;
    const int t   = (bx >> 2) & 63;
    const int gc  = bx & 3;
    const int tid = threadIdx.x;
    for (int i = tid; i < 32 * 300; i += 256) {
        int b = i / 300;
        int d = i - b * 300;
        fls[d * 36 + b] = feat[((size_t)b * 64 + t) * 300 + d];
    }
    __syncthreads();
    const int g = gc * 256 + tid;
    const float* wih = dir ? wih_r : wih_f;
    const float* bih = dir ? bih_r : bih_f;
    const float* bhh = dir ? bhh_r : bhh_f;
    const float* wr  = wih + (size_t)g * 300;
    const float bias = bih[g] + bhh[g];
    float acc[32];
#pragma unroll
    for (int b = 0; b < 32; ++b) acc[b] = 0.0f;
    for (int d = 0; d < 300; d += 4) {
        float4 wv = *(const float4*)(wr + d);
#pragma unroll
        for (int j = 0; j < 4; ++j) {
            float w = (j == 0) ? wv.x : (j == 1) ? wv.y : (j == 2) ? wv.z : wv.w;
            const float* r = &fls[(d + j) * 36];
#pragma unroll
            for (int bq = 0; bq < 8; ++bq) {
                float4 x = *(const float4*)(r + bq * 4);
                acc[bq * 4 + 0] = fmaf(w, x.x, acc[bq * 4 + 0]);
                acc[bq * 4 + 1] = fmaf(w, x.y, acc[bq * 4 + 1]);
                acc[bq * 4 + 2] = fmaf(w, x.z, acc[bq * 4 + 2]);
                acc[bq * 4 + 3] = fmaf(w, x.w, acc[bq * 4 + 3]);
            }
        }
    }
    const int jj      = tid;
    const int js      = jj >> 6;
    const int n_local = ((jj & 63) << 2) | gc;
    const int nt      = n_local >> 5;
    const int lane_lo = n_local & 31;
    float* base = xgF + (((size_t)(dir * 64 + t) * 32) + js * 8 + nt) * 1024;
#pragma unroll
    for (int b = 0; b < 32; ++b) {
        int q    = (b >> 2) & 1;
        int reg  = (b & 3) + ((b >> 3) << 2);
        base[reg * 64 + lane_lo + (q << 5)] = acc[b] + bias;
    }
}

// =====================================================================
// K3 v18 (R23-proven, verbatim): gate-split LSTM, 8 blocks, tagged-
// packet exchange, double-buffered hbuf -> 1 barrier/step.
// 221 us measured, absmax 0.0078.
// =====================================================================
__global__ __launch_bounds__(512) void k_lstm3(const u16* __restrict__ wpk3,
                                               const float* __restrict__ xgF,
                                               u32* __restrict__ hxrec,
                                               float* __restrict__ hseq) {
    __shared__ u32   hbuf[2][32 * 132];       // double-buffered h (bf16 pairs)
    __shared__ float slab[8 * 32 * 36];       // per-wave 32x36 f32 transpose slices
    const int dir = blockIdx.x >> 2;
    const int js  = blockIdx.x & 3;
    const int tid = threadIdx.x;
    const int w   = tid >> 6;                 // n-tile 0..7
    const int l   = tid & 63;
    const int m   = l & 31;
    const int q   = l >> 5;

    v8s Bf[16];
    {
        const u16* wb = wpk3 + ((((size_t)dir * 4 + js) * 8 + w) * 16) * 512 + (size_t)l * 8;
#pragma unroll
        for (int kt = 0; kt < 16; ++kt) Bf[kt] = *(const v8s*)(wb + kt * 512);
    }

    // EW ownership (wave-local): lane l -> batch bl, j-pair jp; handles
    // hidden j_global = js*64 + 8w + 4*jp + c, c=0..3
    const int jp = l & 1;
    const int bl = l >> 1;
    float cst[4], hval[4];
#pragma unroll
    for (int c = 0; c < 4; ++c) { cst[c] = 0.0f; hval[c] = 0.0f; }

    float* hout = hseq + (size_t)dir * 64 * 32 * 256;
    u32* hx_d   = hxrec + (size_t)dir * 2 * 2048 * 4;   // u32 units
    const u32* hx0 = hx_d;                    // parity-0 slot
    const u32* hx1 = hx_d + 2048 * 4;         // parity-1 slot

    // consumer record offsets (R13-identical): 48 peer q64-slots x 32 b
    int roff[3], hoff[3];
#pragma unroll
    for (int i = 0; i < 3; ++i) {
        int flat = i * 512 + tid;
        int b    = flat / 48;
        int r    = flat - b * 48;
        int q64  = r + (r >= js * 16 ? 16 : 0);
        roff[i]  = (b * 64 + q64) * 4;
        hoff[i]  = b * 132 + q64 * 2;
    }
    // producer slot: (batch bl, q64 = js*16 + 2w + jp)
    const int woff = (bl * 64 + js * 16 + 2 * w + jp) * 4;
    const int hown = bl * 132 + (js * 16 + 2 * w + jp) * 2;

    float* sl = &slab[w * 32 * 36];

    // prefetch xg for s=0
    float xcur[16];
    {
        const int t0 = dir ? 63 : 0;
        const float* xb = xgF + (((size_t)(dir * 64 + t0) * 32) + js * 8 + w) * 1024 + l;
#pragma unroll
        for (int r = 0; r < 16; ++r) xcur[r] = xb[r * 64];
    }

    for (int s = 0; s < 64; ++s) {
        u32* hb = hbuf[s & 1];
        v16f acc;
#pragma unroll
        for (int r = 0; r < 16; ++r) acc[r] = xcur[r];
        if (s < 63) {                          // prefetch next step's xg
            const int tn = dir ? (62 - s) : (s + 1);
            const float* xb = xgF + (((size_t)(dir * 64 + tn) * 32) + js * 8 + w) * 1024 + l;
#pragma unroll
            for (int r = 0; r < 16; ++r) xcur[r] = xb[r * 64];
        }

        if (s > 0) {
            // own pack (hval of step s-1)
            u64 pk = (u64)f2bf(hval[0]) | ((u64)f2bf(hval[1]) << 16)
                   | ((u64)f2bf(hval[2]) << 32) | ((u64)f2bf(hval[3]) << 48);
            *(u64*)&hb[hown] = pk;
            // spin for 3 peer records (tag == s)
            const u32* hxs = (s & 1) ? hx1 : hx0;
            const u32* p0 = hxs + roff[0];
            const u32* p1 = hxs + roff[1];
            const u32* p2 = hxs + roff[2];
            v4u v0, v1, v2;
            LD3SYS(v0, v1, v2, p0, p1, p2);
            const u32 ts = (u32)s;
            u32 guard = 0;
            while (v0[2] != ts || v1[2] != ts || v2[2] != ts) {
                if (++guard > (1u << 22)) break;
                LD3SYS(v0, v1, v2, p0, p1, p2);
            }
            *(u64*)&hb[hoff[0]] = (u64)v0[0] | ((u64)v0[1] << 32);
            *(u64*)&hb[hoff[1]] = (u64)v1[0] | ((u64)v1[1] << 32);
            *(u64*)&hb[hoff[2]] = (u64)v2[0] | ((u64)v2[1] << 32);
        } else {
            for (int i = tid; i < 32 * 132; i += 512) hb[i] = 0u;
        }
        __syncthreads();                      // barrier A: hbuf[s&1] ready

        v8s af[16];
#pragma unroll
        for (int kt = 0; kt < 16; ++kt)
            af[kt] = *(const v8s*)&hb[m * 132 + kt * 8 + q * 4];
        // (no barrier B: next step writes hbuf[(s+1)&1]; step s+2's writes
        //  to hbuf[s&1] are fenced by barrier A(s+1))

        // single dependent chain, R13's exact kt order -> bit-identical
#pragma unroll
        for (int kt = 0; kt < 16; ++kt)
            acc = __builtin_amdgcn_mfma_f32_32x32x16_bf16(af[kt], Bf[kt], acc, 0, 0, 0);

        // per-wave transpose: C[row=batch][col=m] -> (bl, gate quads)
#pragma unroll
        for (int r = 0; r < 16; ++r) {
            int row = (r & 3) + 8 * (r >> 2) + 4 * q;
            sl[row * 36 + m] = acc[r];
        }
        // wave-local W->R ordering: compiler inserts lgkmcnt (same buffer)
#pragma unroll
        for (int c = 0; c < 4; ++c) {
            float4 gv = *(const float4*)&sl[bl * 36 + jp * 16 + c * 4];
            float i_ = sigf(gv.x), f_ = sigf(gv.y);
            float g_ = tanhfast(gv.z), o_ = sigf(gv.w);
            cst[c]  = f_ * cst[c] + i_ * g_;
            hval[c] = o_ * tanhfast(cst[c]);
        }

        {
            const int t = dir ? (63 - s) : s;
            u64 pk = (u64)f2bf(hval[0]) | ((u64)f2bf(hval[1]) << 16)
                   | ((u64)f2bf(hval[2]) << 32) | ((u64)f2bf(hval[3]) << 48);
            v4u rec;
            rec[0] = (u32)pk;
            rec[1] = (u32)(pk >> 32);
            rec[2] = (u32)(s + 1);            // tag = step the record feeds
            rec[3] = 0u;
            u32* pw = (u32*)(((s & 1) ? hx0 : hx1) + woff);   // parity (s+1)&1
            ST16SYS(pw, rec);
            float4 hv4 = make_float4(hval[0], hval[1], hval[2], hval[3]);
            *(float4*)&hout[((size_t)t * 32 + bl) * 256 + js * 64 + 8 * w + 4 * jp] = hv4;
        }
    }
}

// =====================================================================
// K4: head (unchanged)
// =====================================================================
__global__ __launch_bounds__(256) void k_head(const float* __restrict__ hseq,
                                              const float* __restrict__ hw,
                                              const float* __restrict__ hb,
                                              float* __restrict__ out) {
    const int id = blockIdx.x * 256 + threadIdx.x;
    const int o  = id & 31;
    const int u  = id >> 5;
    const int b  = u >> 6, t = u & 63;
    const float* pf = hseq + ((size_t)t * 32 + b) * 256;
    const float* pr = hseq + (size_t)64 * 32 * 256 + ((size_t)t * 32 + b) * 256;
    const float* wo = hw + (size_t)o * 512;
    float acc = hb[o];
    for (int j = 0; j < 256; j += 4) {
        float4 wa = *(const float4*)(wo + j);
        float4 wb = *(const float4*)(wo + 256 + j);
        float4 fa = *(const float4*)(pf + j);
        float4 fb = *(const float4*)(pr + j);
        acc = fmaf(wa.x, fa.x, acc); acc = fmaf(wa.y, fa.y, acc);
        acc = fmaf(wa.z, fa.z, acc); acc = fmaf(wa.w, fa.w, acc);
        acc = fmaf(wb.x, fb.x, acc); acc = fmaf(wb.y, fb.y, acc);
        acc = fmaf(wb.z, fb.z, acc); acc = fmaf(wb.w, fb.w, acc);
    }
    out[id] = sigf(acc);
}

// =====================================================================
extern "C" void kernel_launch(void* const* d_in, const int* in_sizes, int n_in,
                              void* d_out, int out_size, void* d_ws, size_t ws_size,
                              hipStream_t stream) {
    const int*   dlg   = (const int*)d_in[0];
    const float* emb   = (const float*)d_in[1];
    const float* w3    = (const float*)d_in[2];  const float* b3    = (const float*)d_in[3];
    const float* w4    = (const float*)d_in[4];  const float* b4    = (const float*)d_in[5];
    const float* w5    = (const float*)d_in[6];  const float* b5    = (const float*)d_in[7];
    const float* wih_f = (const float*)d_in[8];  const float* whh_f = (const float*)d_in[9];
    const float* bih_f = (const float*)d_in[10]; const float* bhh_f = (const float*)d_in[11];
    const float* wih_r = (const float*)d_in[12]; const float* whh_r = (const float*)d_in[13];
    const float* bih_r = (const float*)d_in[14]; const float* bhh_r = (const float*)d_in[15];
    const float* hw    = (const float*)d_in[16]; const float* hb    = (const float*)d_in[17];
    float* out = (float*)d_out;

    float* f     = (float*)d_ws;
    float* feat  = f;                         // 614400
    float* xgF   = f + 614400;                // 4194304
    float* hseq  = f + 4808704;               // 1048576
    u16*   wkr   = (u16*)(f + 5857280);       // 466944 u16
    u16*   wpk3  = (u16*)(f + 6090752);       // 524288 u16
    u32*   hxrec = (u32*)(f + 6352896);       // 8192 records x 16B
    // total ~25.5 MB

    hipLaunchKernelGGL(k_prep, dim3(CPREP_NB + 2048), dim3(256), 0, stream,
                       w3, w4, w5, wkr, (v4u*)hxrec, whh_f, whh_r, wpk3);
    hipLaunchKernelGGL(k_conv_mfma, dim3(1024), dim3(384), 0, stream,
                       dlg, emb, wkr, b3, b4, b5, feat);
    hipLaunchKernelGGL(k_xg, dim3(512), dim3(256), 0, stream,
                       feat, wih_f, bih_f, bhh_f, wih_r, bih_r, bhh_r, xgF);
    hipLaunchKernelGGL(k_lstm3, dim3(8), dim3(512), 0, stream,
                       wpk3, xgF, hxrec, hseq);
    hipLaunchKernelGGL(k_head, dim3(256), dim3(256), 0, stream,
                       hseq, hw, hb, out);
}